// Round 2
// baseline (945.280 us; speedup 1.0000x reference)
//
#include <hip/hip_runtime.h>
#include <cstdint>

#define BN 8
#define HH 512
#define WW 640
#define HWp (HH*WW)
#define NPIX (BN*HWp)
#define RAD 2
#define TOPK 4096
#define NBINS 65536
#define CAND_CAP 8192

// workspace layout (bytes) -- total ~7.9 MB
#define OFF_M     0
#define OFF_U     (OFF_M + NPIX)
#define OFF_HIST  (OFF_U + NPIX)
#define OFF_CNT   (OFF_HIST + BN*NBINS*4)
#define OFF_TBIN  (OFF_CNT + 128)
#define OFF_CAND  (OFF_TBIN + 128)
#define OFF_KPIDX (OFF_CAND + BN*CAND_CAP*8)

__global__ void k_zero(unsigned* __restrict__ p, int n) {
    int i = blockIdx.x * blockDim.x + threadIdx.x;
    if (i < n) p[i] = 0u;
}

// max_mask = (S == maxpool5(S))
__global__ void k_mask(const float* __restrict__ S, uint8_t* __restrict__ M) {
    int gid = blockIdx.x * blockDim.x + threadIdx.x;
    if (gid >= NPIX) return;
    int b = gid / HWp, p = gid - b * HWp;
    int y = p / WW, x = p - y * WW;
    const float* img = S + b * HWp;
    int y0 = y - RAD < 0 ? 0 : y - RAD, y1 = y + RAD >= HH ? HH - 1 : y + RAD;
    int x0 = x - RAD < 0 ? 0 : x - RAD, x1 = x + RAD >= WW ? WW - 1 : x + RAD;
    float c = img[p];
    float mx = c;
    for (int yy = y0; yy <= y1; ++yy) {
        const float* row = img + yy * WW;
        for (int xx = x0; xx <= x1; ++xx) mx = fmaxf(mx, row[xx]);
    }
    M[gid] = (c == mx) ? (uint8_t)1 : (uint8_t)0;
}

// U = dilate5(M) > 0
__global__ void k_dilate(const uint8_t* __restrict__ M, uint8_t* __restrict__ U) {
    int gid = blockIdx.x * blockDim.x + threadIdx.x;
    if (gid >= NPIX) return;
    int b = gid / HWp, p = gid - b * HWp;
    int y = p / WW, x = p - y * WW;
    const uint8_t* m = M + b * HWp;
    int y0 = y - RAD < 0 ? 0 : y - RAD, y1 = y + RAD >= HH ? HH - 1 : y + RAD;
    int x0 = x - RAD < 0 ? 0 : x - RAD, x1 = x + RAD >= WW ? WW - 1 : x + RAD;
    unsigned acc = 0;
    for (int yy = y0; yy <= y1; ++yy) {
        const uint8_t* row = m + yy * WW;
        for (int xx = x0; xx <= x1; ++xx) acc |= row[xx];
    }
    U[gid] = acc ? (uint8_t)1 : (uint8_t)0;
}

// supp_scores = U?0:S; new_max = (supp == maxpool5(supp)); M |= new_max & ~U
__global__ void k_update(const float* __restrict__ S, const uint8_t* __restrict__ U,
                         uint8_t* __restrict__ M) {
    int gid = blockIdx.x * blockDim.x + threadIdx.x;
    if (gid >= NPIX) return;
    int b = gid / HWp, p = gid - b * HWp;
    int y = p / WW, x = p - y * WW;
    const float* img = S + b * HWp;
    const uint8_t* u = U + b * HWp;
    int y0 = y - RAD < 0 ? 0 : y - RAD, y1 = y + RAD >= HH ? HH - 1 : y + RAD;
    int x0 = x - RAD < 0 ? 0 : x - RAD, x1 = x + RAD >= WW ? WW - 1 : x + RAD;
    float mx = -1e30f;
    for (int yy = y0; yy <= y1; ++yy) {
        const float* row = img + yy * WW;
        const uint8_t* urow = u + yy * WW;
        for (int xx = x0; xx <= x1; ++xx) {
            float v = urow[xx] ? 0.f : row[xx];
            mx = fmaxf(mx, v);
        }
    }
    uint8_t uc = u[p];
    if (!uc && img[p] == mx) M[gid] = (uint8_t)1;
}

// histogram high-16 float bits of final keypoint scores (mask && !border)
__global__ void k_hist(const float* __restrict__ S, const uint8_t* __restrict__ M,
                       unsigned* __restrict__ hist) {
    int gid = blockIdx.x * blockDim.x + threadIdx.x;
    if (gid >= NPIX) return;
    int b = gid / HWp, p = gid - b * HWp;
    int y = p / WW, x = p - y * WW;
    if (M[gid] && y >= RAD + 1 && y < HH - RAD && x >= RAD + 1 && x < WW - RAD) {
        float v = S[gid];
        if (v != 0.f) {
            unsigned bits = __float_as_uint(v);
            atomicAdd(&hist[b * NBINS + (bits >> 16)], 1u);
        }
    }
}

// per-batch: threshold bin T s.t. count(bins > T) < TOPK <= count(bins >= T)
__global__ __launch_bounds__(1024) void k_scan(const unsigned* __restrict__ hist,
                                               int* __restrict__ Tbin) {
    __shared__ unsigned b0[1024], b1[1024];
    int b = blockIdx.x, t = threadIdx.x;
    const unsigned* h = hist + b * NBINS;
    int base = NBINS - (t + 1) * 64;     // chunk t = bins [base, base+63], descending
    unsigned s = 0;
    for (int i = 0; i < 64; ++i) s += h[base + i];
    b0[t] = s;
    __syncthreads();
    unsigned* src = b0; unsigned* dst = b1;
    for (int off = 1; off < 1024; off <<= 1) {
        unsigned v = src[t];
        if (t >= off) v += src[t - off];
        dst[t] = v;
        __syncthreads();
        unsigned* tmp = src; src = dst; dst = tmp;
    }
    unsigned incl = src[t];
    unsigned excl = incl - s;
    unsigned total = src[1023];
    const unsigned K = TOPK;
    if (excl < K && K <= incl) {
        unsigned run = excl;
        for (int i = 0; i < 64; ++i) {
            int bin = NBINS - 1 - t * 64 - i;
            unsigned c = h[bin];
            if (run < K && K <= run + c) { Tbin[b] = bin; break; }
            run += c;
        }
    }
    if (t == 1023 && total < K) Tbin[b] = 0;
}

// gather candidates with bin >= T (key = bits<<32 | ~idx)
__global__ void k_compact(const float* __restrict__ S, const uint8_t* __restrict__ M,
                          const int* __restrict__ Tbin,
                          unsigned* __restrict__ cnt, unsigned long long* __restrict__ cand) {
    int gid = blockIdx.x * blockDim.x + threadIdx.x;
    if (gid >= NPIX) return;
    int b = gid / HWp, p = gid - b * HWp;
    int y = p / WW, x = p - y * WW;
    if (!M[gid] || y < RAD + 1 || y >= HH - RAD || x < RAD + 1 || x >= WW - RAD) return;
    float v = S[gid];
    if (v == 0.f) return;
    unsigned bits = __float_as_uint(v);
    if ((int)(bits >> 16) >= Tbin[b]) {
        unsigned pos = atomicAdd(&cnt[b], 1u);
        if (pos < CAND_CAP) {
            cand[b * CAND_CAP + pos] =
                ((unsigned long long)bits << 32) | (unsigned)(~(unsigned)p);
        }
    }
}

// one block per batch: bitonic-sort 8192 keys descending in LDS, emit top 4096 indices
__global__ __launch_bounds__(1024) void k_sort(const unsigned* __restrict__ cnt,
                                               const unsigned long long* __restrict__ cand,
                                               int* __restrict__ kp) {
    __shared__ unsigned long long keys[CAND_CAP];
    int b = blockIdx.x, t = threadIdx.x;
    unsigned nr = cnt[b];
    if (nr > CAND_CAP) nr = CAND_CAP;
    for (int i = t; i < CAND_CAP; i += 1024)
        keys[i] = (i < (int)nr) ? cand[b * CAND_CAP + i] : 0ull;
    __syncthreads();
    for (int k = 2; k <= CAND_CAP; k <<= 1) {
        for (int j = k >> 1; j > 0; j >>= 1) {
            for (int i = t; i < CAND_CAP; i += 1024) {
                int ixj = i ^ j;
                if (ixj > i) {
                    bool asc = (i & k) != 0;   // flipped -> overall descending
                    unsigned long long a = keys[i], c = keys[ixj];
                    bool sw = asc ? (a > c) : (a < c);
                    if (sw) { keys[i] = c; keys[ixj] = a; }
                }
            }
            __syncthreads();
        }
    }
    for (int i = t; i < TOPK; i += 1024) {
        unsigned long long key = keys[i];
        int idx;
        if (key != 0ull) idx = (int)(~(unsigned)(key & 0xFFFFFFFFull));
        else             idx = i - (int)nr;   // fallback (fewer than TOPK nonzero)
        kp[b * TOPK + i] = idx;
    }
}

// per-keypoint: patch softmax soft-argmax + disp + normalized coords + bilinear score
__global__ void k_kp(const float* __restrict__ S, const int* __restrict__ kp,
                     float* __restrict__ out) {
    int g = blockIdx.x * blockDim.x + threadIdx.x;
    if (g >= BN * TOPK) return;
    int b = g >> 12;
    int idx = kp[g];
    int y = idx / WW, x = idx - y * WW;
    const float* img = S + b * HWp;
    float ps[25];
#pragma unroll
    for (int di = 0; di < 5; ++di) {
#pragma unroll
        for (int dj = 0; dj < 5; ++dj) {
            int yy = y + di - RAD, xx = x + dj - RAD;
            bool ok = (yy >= 0) && (yy < HH) && (xx >= 0) && (xx < WW);
            ps[di * 5 + dj] = ok ? img[yy * WW + xx] : 0.f;
        }
    }
    float mx = ps[0];
#pragma unroll
    for (int p = 1; p < 25; ++p) mx = fmaxf(mx, ps[p]);
    float ssum = 0.f, sx = 0.f, sy = 0.f, sg2 = 0.f;
#pragma unroll
    for (int p = 0; p < 25; ++p) {
        float dx = (float)(p % 5) - 2.f;
        float dy = (float)(p / 5) - 2.f;
        float e = expf((ps[p] - mx) / 0.1f);
        ssum += e;
        sx += e * dx;
        sy += e * dy;
        sg2 += e * (dx * dx + dy * dy);
    }
    float xr = sx / ssum, yr = sy / ssum;
    float disp = (sg2 - 2.f * (xr * sx + yr * sy) + (xr * xr + yr * yr) * ssum)
                 / (4.f * ssum);
    float kxn = ((float)x + xr) / (float)(WW - 1) * 2.f - 1.f;
    float kyn = ((float)y + yr) / (float)(HH - 1) * 2.f - 1.f;
    out[2 * g]     = kxn;
    out[2 * g + 1] = kyn;
    float px = (kxn + 1.f) * 0.5f * (float)(WW - 1);
    float py = (kyn + 1.f) * 0.5f * (float)(HH - 1);
    float x0 = floorf(px), y0f = floorf(py);
    float wx = px - x0, wy = py - y0f;
    int x0i = (int)fminf(fmaxf(x0, 0.f), (float)(WW - 1));
    int x1i = (int)fminf(fmaxf(x0 + 1.f, 0.f), (float)(WW - 1));
    int y0i = (int)fminf(fmaxf(y0f, 0.f), (float)(HH - 1));
    int y1i = (int)fminf(fmaxf(y0f + 1.f, 0.f), (float)(HH - 1));
    float v00 = img[y0i * WW + x0i], v01 = img[y0i * WW + x1i];
    float v10 = img[y1i * WW + x0i], v11 = img[y1i * WW + x1i];
    float sc = v00 * (1.f - wx) * (1.f - wy) + v01 * wx * (1.f - wy)
             + v10 * (1.f - wx) * wy + v11 * wx * wy;
    out[BN * TOPK * 2 + g] = sc;
    out[BN * TOPK * 3 + g] = disp;
}

extern "C" void kernel_launch(void* const* d_in, const int* in_sizes, int n_in,
                              void* d_out, int out_size, void* d_ws, size_t ws_size,
                              hipStream_t stream) {
    const float* S = (const float*)d_in[0];
    float* out = (float*)d_out;
    char* ws = (char*)d_ws;

    uint8_t*            M     = (uint8_t*)(ws + OFF_M);
    uint8_t*            U     = (uint8_t*)(ws + OFF_U);
    unsigned*           hist  = (unsigned*)(ws + OFF_HIST);
    unsigned*           cnt   = (unsigned*)(ws + OFF_CNT);
    int*                Tbin  = (int*)(ws + OFF_TBIN);
    unsigned long long* cand  = (unsigned long long*)(ws + OFF_CAND);
    int*                kpidx = (int*)(ws + OFF_KPIDX);

    // zero hist + counters (ws is poisoned each launch)
    int zwords = (BN * NBINS * 4 + 128) / 4;
    k_zero<<<(zwords + 255) / 256, 256, 0, stream>>>(hist, zwords);

    int nblk = (NPIX + 255) / 256;
    k_mask<<<nblk, 256, 0, stream>>>(S, M);
    k_dilate<<<nblk, 256, 0, stream>>>(M, U);
    k_update<<<nblk, 256, 0, stream>>>(S, U, M);
    k_dilate<<<nblk, 256, 0, stream>>>(M, U);
    k_update<<<nblk, 256, 0, stream>>>(S, U, M);
    k_hist<<<nblk, 256, 0, stream>>>(S, M, hist);
    k_scan<<<BN, 1024, 0, stream>>>(hist, Tbin);
    k_compact<<<nblk, 256, 0, stream>>>(S, M, Tbin, cnt, cand);
    k_sort<<<BN, 1024, 0, stream>>>(cnt, cand, kpidx);
    k_kp<<<(BN * TOPK + 255) / 256, 256, 0, stream>>>(S, kpidx, out);
}

// Round 7
// 548.833 us; speedup vs baseline: 1.7223x; 1.7223x over previous
//
#include <hip/hip_runtime.h>
#include <cstdint>

#define BN 8
#define HH 512
#define WW 640
#define HWp (HH*WW)
#define NPIX (BN*HWp)
#define RAD 2
#define TOPK 4096
#define NBINS 65536
#define CAND_CAP 8192

// workspace layout (bytes)
#define OFF_M     0
#define OFF_U     (OFF_M + NPIX)
#define OFF_HIST  (OFF_U + NPIX)
#define OFF_CNT   (OFF_HIST + BN*NBINS*4)       // 8 counters, each on own 128B line
#define OFF_TBIN  (OFF_CNT + 1024)
#define OFF_CAND  (OFF_TBIN + 128)
#define OFF_KPIDX (OFF_CAND + BN*CAND_CAP*8)

#define CNT_STRIDE 32   // uints; 128 bytes between per-batch counters

__global__ void k_zero(unsigned* __restrict__ p, int n) {
    int i = blockIdx.x * blockDim.x + threadIdx.x;
    if (i < n) p[i] = 0u;
}

// max_mask = (S == maxpool5(S))
__global__ void k_mask(const float* __restrict__ S, uint8_t* __restrict__ M) {
    int gid = blockIdx.x * blockDim.x + threadIdx.x;
    if (gid >= NPIX) return;
    int b = gid / HWp, p = gid - b * HWp;
    int y = p / WW, x = p - y * WW;
    const float* img = S + b * HWp;
    float c = img[p];
    float mx = c;
    if (y >= RAD && y < HH - RAD && x >= RAD && x < WW - RAD) {
        const float* base = img + p - RAD * WW - RAD;
#pragma unroll
        for (int dy = 0; dy < 5; ++dy)
#pragma unroll
            for (int dx = 0; dx < 5; ++dx)
                mx = fmaxf(mx, base[dy * WW + dx]);
    } else {
        int y0 = y - RAD < 0 ? 0 : y - RAD, y1 = y + RAD >= HH ? HH - 1 : y + RAD;
        int x0 = x - RAD < 0 ? 0 : x - RAD, x1 = x + RAD >= WW ? WW - 1 : x + RAD;
        for (int yy = y0; yy <= y1; ++yy) {
            const float* row = img + yy * WW;
            for (int xx = x0; xx <= x1; ++xx) mx = fmaxf(mx, row[xx]);
        }
    }
    M[gid] = (c == mx) ? (uint8_t)1 : (uint8_t)0;
}

// U = dilate5(M) > 0
__global__ void k_dilate(const uint8_t* __restrict__ M, uint8_t* __restrict__ U) {
    int gid = blockIdx.x * blockDim.x + threadIdx.x;
    if (gid >= NPIX) return;
    int b = gid / HWp, p = gid - b * HWp;
    int y = p / WW, x = p - y * WW;
    const uint8_t* m = M + b * HWp;
    unsigned acc = 0;
    if (y >= RAD && y < HH - RAD && x >= RAD && x < WW - RAD) {
        const uint8_t* base = m + p - RAD * WW - RAD;
#pragma unroll
        for (int dy = 0; dy < 5; ++dy)
#pragma unroll
            for (int dx = 0; dx < 5; ++dx)
                acc |= base[dy * WW + dx];
    } else {
        int y0 = y - RAD < 0 ? 0 : y - RAD, y1 = y + RAD >= HH ? HH - 1 : y + RAD;
        int x0 = x - RAD < 0 ? 0 : x - RAD, x1 = x + RAD >= WW ? WW - 1 : x + RAD;
        for (int yy = y0; yy <= y1; ++yy) {
            const uint8_t* row = m + yy * WW;
            for (int xx = x0; xx <= x1; ++xx) acc |= row[xx];
        }
    }
    U[gid] = acc ? (uint8_t)1 : (uint8_t)0;
}

// supp = U?0:S; new_max = (supp == maxpool5(supp)); M |= new_max & ~U
__global__ void k_update(const float* __restrict__ S, const uint8_t* __restrict__ U,
                         uint8_t* __restrict__ M) {
    int gid = blockIdx.x * blockDim.x + threadIdx.x;
    if (gid >= NPIX) return;
    int b = gid / HWp, p = gid - b * HWp;
    int y = p / WW, x = p - y * WW;
    const float* img = S + b * HWp;
    const uint8_t* u = U + b * HWp;
    float mx = -1e30f;
    if (y >= RAD && y < HH - RAD && x >= RAD && x < WW - RAD) {
        const float* sbase = img + p - RAD * WW - RAD;
        const uint8_t* ubase = u + p - RAD * WW - RAD;
#pragma unroll
        for (int dy = 0; dy < 5; ++dy)
#pragma unroll
            for (int dx = 0; dx < 5; ++dx) {
                float v = ubase[dy * WW + dx] ? 0.f : sbase[dy * WW + dx];
                mx = fmaxf(mx, v);
            }
    } else {
        int y0 = y - RAD < 0 ? 0 : y - RAD, y1 = y + RAD >= HH ? HH - 1 : y + RAD;
        int x0 = x - RAD < 0 ? 0 : x - RAD, x1 = x + RAD >= WW ? WW - 1 : x + RAD;
        for (int yy = y0; yy <= y1; ++yy) {
            const float* row = img + yy * WW;
            const uint8_t* urow = u + yy * WW;
            for (int xx = x0; xx <= x1; ++xx) {
                float v = urow[xx] ? 0.f : row[xx];
                mx = fmaxf(mx, v);
            }
        }
    }
    uint8_t uc = u[p];
    if (!uc && img[p] == mx) M[gid] = (uint8_t)1;
}

// second update FUSED with histogram of final keypoint scores
__global__ void k_update_hist(const float* __restrict__ S, const uint8_t* __restrict__ U,
                              uint8_t* __restrict__ M, unsigned* __restrict__ hist) {
    int gid = blockIdx.x * blockDim.x + threadIdx.x;
    if (gid >= NPIX) return;
    int b = gid / HWp, p = gid - b * HWp;
    int y = p / WW, x = p - y * WW;
    const float* img = S + b * HWp;
    const uint8_t* u = U + b * HWp;
    float mx = -1e30f;
    if (y >= RAD && y < HH - RAD && x >= RAD && x < WW - RAD) {
        const float* sbase = img + p - RAD * WW - RAD;
        const uint8_t* ubase = u + p - RAD * WW - RAD;
#pragma unroll
        for (int dy = 0; dy < 5; ++dy)
#pragma unroll
            for (int dx = 0; dx < 5; ++dx) {
                float v = ubase[dy * WW + dx] ? 0.f : sbase[dy * WW + dx];
                mx = fmaxf(mx, v);
            }
    } else {
        int y0 = y - RAD < 0 ? 0 : y - RAD, y1 = y + RAD >= HH ? HH - 1 : y + RAD;
        int x0 = x - RAD < 0 ? 0 : x - RAD, x1 = x + RAD >= WW ? WW - 1 : x + RAD;
        for (int yy = y0; yy <= y1; ++yy) {
            const float* row = img + yy * WW;
            const uint8_t* urow = u + yy * WW;
            for (int xx = x0; xx <= x1; ++xx) {
                float v = urow[xx] ? 0.f : row[xx];
                mx = fmaxf(mx, v);
            }
        }
    }
    uint8_t uc = u[p];
    float c = img[p];
    uint8_t final_m = M[gid];
    if (!uc && c == mx) { final_m = 1; M[gid] = 1; }
    if (final_m && y >= RAD + 1 && y < HH - RAD && x >= RAD + 1 && x < WW - RAD
        && c != 0.f) {
        unsigned bits = __float_as_uint(c);
        atomicAdd(&hist[b * NBINS + (bits >> 16)], 1u);
    }
}

// per-batch: threshold bin T s.t. count(bins > T) < TOPK <= count(bins >= T)
__global__ __launch_bounds__(1024) void k_scan(const unsigned* __restrict__ hist,
                                               int* __restrict__ Tbin) {
    __shared__ unsigned b0[1024], b1[1024];
    int b = blockIdx.x, t = threadIdx.x;
    const unsigned* h = hist + b * NBINS;
    int base = NBINS - (t + 1) * 64;
    unsigned s = 0;
    for (int i = 0; i < 64; ++i) s += h[base + i];
    b0[t] = s;
    __syncthreads();
    unsigned* src = b0; unsigned* dst = b1;
    for (int off = 1; off < 1024; off <<= 1) {
        unsigned v = src[t];
        if (t >= off) v += src[t - off];
        dst[t] = v;
        __syncthreads();
        unsigned* tmp = src; src = dst; dst = tmp;
    }
    unsigned incl = src[t];
    unsigned excl = incl - s;
    unsigned total = src[1023];
    const unsigned K = TOPK;
    if (excl < K && K <= incl) {
        unsigned run = excl;
        for (int i = 0; i < 64; ++i) {
            int bin = NBINS - 1 - t * 64 - i;
            unsigned c = h[bin];
            if (run < K && K <= run + c) { Tbin[b] = bin; break; }
            run += c;
        }
    }
    if (t == 1023 && total < K) Tbin[b] = 0;
}

// block-aggregated compaction: 1 LDS counter per block, 1 global atomic per block
__global__ void k_compact(const float* __restrict__ S, const uint8_t* __restrict__ M,
                          const int* __restrict__ Tbin,
                          unsigned* __restrict__ cnt, unsigned long long* __restrict__ cand) {
    __shared__ unsigned lcnt, lbase;
    int gid = blockIdx.x * 256 + threadIdx.x;   // HWp % 256 == 0 -> block within one batch
    int b = gid / HWp, p = gid - b * HWp;
    int y = p / WW, x = p - y * WW;
    if (threadIdx.x == 0) lcnt = 0;
    __syncthreads();
    bool win = false;
    unsigned mypos = 0;
    unsigned long long key = 0;
    if (M[gid] && y >= RAD + 1 && y < HH - RAD && x >= RAD + 1 && x < WW - RAD) {
        float v = S[gid];
        if (v != 0.f) {
            unsigned bits = __float_as_uint(v);
            if ((int)(bits >> 16) >= Tbin[b]) {
                mypos = atomicAdd(&lcnt, 1u);
                key = ((unsigned long long)bits << 32) | (unsigned)(~(unsigned)p);
                win = true;
            }
        }
    }
    __syncthreads();
    if (threadIdx.x == 0 && lcnt)
        lbase = atomicAdd(&cnt[b * CNT_STRIDE], lcnt);
    __syncthreads();
    if (win) {
        unsigned pos = lbase + mypos;
        if (pos < CAND_CAP) cand[b * CAND_CAP + pos] = key;
    }
}

// one block per batch: bitonic-sort 8192 keys descending, emit top 4096 indices
__global__ __launch_bounds__(1024) void k_sort(const unsigned* __restrict__ cnt,
                                               const unsigned long long* __restrict__ cand,
                                               int* __restrict__ kp) {
    __shared__ unsigned long long keys[CAND_CAP];
    int b = blockIdx.x, t = threadIdx.x;
    unsigned nr = cnt[b * CNT_STRIDE];
    if (nr > CAND_CAP) nr = CAND_CAP;
    for (int i = t; i < CAND_CAP; i += 1024)
        keys[i] = (i < (int)nr) ? cand[b * CAND_CAP + i] : 0ull;
    __syncthreads();
    for (int k = 2; k <= CAND_CAP; k <<= 1) {
        for (int j = k >> 1; j > 0; j >>= 1) {
            for (int i = t; i < CAND_CAP; i += 1024) {
                int ixj = i ^ j;
                if (ixj > i) {
                    bool asc = (i & k) != 0;
                    unsigned long long a = keys[i], c = keys[ixj];
                    bool sw = asc ? (a > c) : (a < c);
                    if (sw) { keys[i] = c; keys[ixj] = a; }
                }
            }
            __syncthreads();
        }
    }
    for (int i = t; i < TOPK; i += 1024) {
        unsigned long long key = keys[i];
        int idx;
        if (key != 0ull) idx = (int)(~(unsigned)(key & 0xFFFFFFFFull));
        else             idx = i - (int)nr;
        kp[b * TOPK + i] = idx;
    }
}

// per-keypoint: softmax soft-argmax + disp + normalized coords + bilinear score
__global__ void k_kp(const float* __restrict__ S, const int* __restrict__ kp,
                     float* __restrict__ out) {
    int g = blockIdx.x * blockDim.x + threadIdx.x;
    if (g >= BN * TOPK) return;
    int b = g >> 12;
    int idx = kp[g];
    int y = idx / WW, x = idx - y * WW;
    const float* img = S + b * HWp;
    float ps[25];
#pragma unroll
    for (int di = 0; di < 5; ++di) {
#pragma unroll
        for (int dj = 0; dj < 5; ++dj) {
            int yy = y + di - RAD, xx = x + dj - RAD;
            bool ok = (yy >= 0) && (yy < HH) && (xx >= 0) && (xx < WW);
            ps[di * 5 + dj] = ok ? img[yy * WW + xx] : 0.f;
        }
    }
    float mx = ps[0];
#pragma unroll
    for (int p = 1; p < 25; ++p) mx = fmaxf(mx, ps[p]);
    float ssum = 0.f, sx = 0.f, sy = 0.f, sg2 = 0.f;
#pragma unroll
    for (int p = 0; p < 25; ++p) {
        float dx = (float)(p % 5) - 2.f;
        float dy = (float)(p / 5) - 2.f;
        float e = expf((ps[p] - mx) / 0.1f);
        ssum += e;
        sx += e * dx;
        sy += e * dy;
        sg2 += e * (dx * dx + dy * dy);
    }
    float xr = sx / ssum, yr = sy / ssum;
    float disp = (sg2 - 2.f * (xr * sx + yr * sy) + (xr * xr + yr * yr) * ssum)
                 / (4.f * ssum);
    float kxn = ((float)x + xr) / (float)(WW - 1) * 2.f - 1.f;
    float kyn = ((float)y + yr) / (float)(HH - 1) * 2.f - 1.f;
    out[2 * g]     = kxn;
    out[2 * g + 1] = kyn;
    float px = (kxn + 1.f) * 0.5f * (float)(WW - 1);
    float py = (kyn + 1.f) * 0.5f * (float)(HH - 1);
    float x0 = floorf(px), y0f = floorf(py);
    float wx = px - x0, wy = py - y0f;
    int x0i = (int)fminf(fmaxf(x0, 0.f), (float)(WW - 1));
    int x1i = (int)fminf(fmaxf(x0 + 1.f, 0.f), (float)(WW - 1));
    int y0i = (int)fminf(fmaxf(y0f, 0.f), (float)(HH - 1));
    int y1i = (int)fminf(fmaxf(y0f + 1.f, 0.f), (float)(HH - 1));
    float v00 = img[y0i * WW + x0i], v01 = img[y0i * WW + x1i];
    float v10 = img[y1i * WW + x0i], v11 = img[y1i * WW + x1i];
    float sc = v00 * (1.f - wx) * (1.f - wy) + v01 * wx * (1.f - wy)
             + v10 * (1.f - wx) * wy + v11 * wx * wy;
    out[BN * TOPK * 2 + g] = sc;
    out[BN * TOPK * 3 + g] = disp;
}

extern "C" void kernel_launch(void* const* d_in, const int* in_sizes, int n_in,
                              void* d_out, int out_size, void* d_ws, size_t ws_size,
                              hipStream_t stream) {
    const float* S = (const float*)d_in[0];
    float* out = (float*)d_out;
    char* ws = (char*)d_ws;

    uint8_t*            M     = (uint8_t*)(ws + OFF_M);
    uint8_t*            U     = (uint8_t*)(ws + OFF_U);
    unsigned*           hist  = (unsigned*)(ws + OFF_HIST);
    unsigned*           cnt   = (unsigned*)(ws + OFF_CNT);
    int*                Tbin  = (int*)(ws + OFF_TBIN);
    unsigned long long* cand  = (unsigned long long*)(ws + OFF_CAND);
    int*                kpidx = (int*)(ws + OFF_KPIDX);

    // zero hist + padded counters (contiguous)
    int zwords = (BN * NBINS * 4 + 1024) / 4;
    k_zero<<<(zwords + 255) / 256, 256, 0, stream>>>(hist, zwords);

    int nblk = (NPIX + 255) / 256;
    k_mask<<<nblk, 256, 0, stream>>>(S, M);
    k_dilate<<<nblk, 256, 0, stream>>>(M, U);
    k_update<<<nblk, 256, 0, stream>>>(S, U, M);
    k_dilate<<<nblk, 256, 0, stream>>>(M, U);
    k_update_hist<<<nblk, 256, 0, stream>>>(S, U, M, hist);
    k_scan<<<BN, 1024, 0, stream>>>(hist, Tbin);
    k_compact<<<nblk, 256, 0, stream>>>(S, M, Tbin, cnt, cand);
    k_sort<<<BN, 1024, 0, stream>>>(cnt, cand, kpidx);
    k_kp<<<(BN * TOPK + 255) / 256, 256, 0, stream>>>(S, kpidx, out);
}

// Round 9
// 479.173 us; speedup vs baseline: 1.9727x; 1.1454x over previous
//
#include <hip/hip_runtime.h>
#include <cstdint>

#define BN 8
#define HH 512
#define WW 640
#define HWp (HH*WW)
#define NPIX (BN*HWp)
#define RAD 2
#define TOPK 4096
#define NBINS 65536
#define CAND_CAP 8192

// workspace layout (bytes)
#define OFF_M     0
#define OFF_U     (OFF_M + NPIX)
#define OFF_HIST  (OFF_U + NPIX)
#define OFF_CNT   (OFF_HIST + BN*NBINS*4)
#define OFF_TBIN  (OFF_CNT + 1024)
#define OFF_CAND  (OFF_TBIN + 128)
#define OFF_KPIDX (OFF_CAND + BN*CAND_CAP*8)

#define CNT_STRIDE 32   // uints; 128 bytes between per-batch counters

__global__ void k_zero(unsigned* __restrict__ p, int n) {
    int i = blockIdx.x * blockDim.x + threadIdx.x;
    if (i < n) p[i] = 0u;
}

__device__ __forceinline__ unsigned bx(unsigned v, int k) { return (v >> (k * 8)) & 0xFFu; }

// ---- 4-wide max_mask: M = (S == maxpool5(S)) ----
__global__ void k_mask4(const float* __restrict__ S, uint8_t* __restrict__ M) {
    int g = blockIdx.x * 256 + threadIdx.x;
    int gid4 = g * 4;
    int b = gid4 / HWp, p = gid4 - b * HWp;
    int y = p / WW, x0 = p - y * WW;
    const float* img = S + b * HWp;
    float o4[4], c4[4];
    if (y >= RAD && y < HH - RAD && x0 >= 4 && x0 <= WW - 8) {
        float cm[12];
#pragma unroll
        for (int dy = 0; dy < 5; ++dy) {
            const float* sr = img + (y - 2 + dy) * WW + x0 - 4;
            float4 fa = *(const float4*)sr;
            float4 fb = *(const float4*)(sr + 4);
            float4 fc = *(const float4*)(sr + 8);
            float s[12] = {fa.x, fa.y, fa.z, fa.w, fb.x, fb.y, fb.z, fb.w,
                           fc.x, fc.y, fc.z, fc.w};
            if (dy == 2) { c4[0] = fb.x; c4[1] = fb.y; c4[2] = fb.z; c4[3] = fb.w; }
#pragma unroll
            for (int k = 0; k < 12; ++k)
                cm[k] = (dy == 0) ? s[k] : fmaxf(cm[k], s[k]);
        }
#pragma unroll
        for (int i = 0; i < 4; ++i)
            o4[i] = fmaxf(fmaxf(fmaxf(cm[i + 2], cm[i + 3]),
                                fmaxf(cm[i + 4], cm[i + 5])), cm[i + 6]);
    } else {
        for (int i = 0; i < 4; ++i) {
            int x = x0 + i;
            float c = img[y * WW + x];
            float mx = c;
            int y0 = y - RAD < 0 ? 0 : y - RAD, y1 = y + RAD >= HH ? HH - 1 : y + RAD;
            int xx0 = x - RAD < 0 ? 0 : x - RAD, xx1 = x + RAD >= WW ? WW - 1 : x + RAD;
            for (int yy = y0; yy <= y1; ++yy) {
                const float* row = img + yy * WW;
                for (int xx = xx0; xx <= xx1; ++xx) mx = fmaxf(mx, row[xx]);
            }
            o4[i] = mx; c4[i] = c;
        }
    }
    unsigned mw = 0;
#pragma unroll
    for (int i = 0; i < 4; ++i)
        if (c4[i] == o4[i]) mw |= 1u << (8 * i);
    *(unsigned*)(M + gid4) = mw;
}

// ---- 4-wide dilate: U = dilate5(M) > 0 ----
__global__ void k_dilate4(const uint8_t* __restrict__ M, uint8_t* __restrict__ U) {
    int g = blockIdx.x * 256 + threadIdx.x;
    int gid4 = g * 4;
    int b = gid4 / HWp, p = gid4 - b * HWp;
    int y = p / WW, x0 = p - y * WW;
    const uint8_t* m = M + b * HWp;
    unsigned uw = 0;
    if (y >= RAD && y < HH - RAD && x0 >= 4 && x0 <= WW - 8) {
        unsigned v0 = 0, v1 = 0, v2 = 0;
#pragma unroll
        for (int dy = 0; dy < 5; ++dy) {
            const unsigned* r = (const unsigned*)(m + (y - 2 + dy) * WW + x0 - 4);
            v0 |= r[0]; v1 |= r[1]; v2 |= r[2];
        }
        unsigned Bt[12];
#pragma unroll
        for (int k = 0; k < 4; ++k) {
            Bt[k] = bx(v0, k); Bt[k + 4] = bx(v1, k); Bt[k + 8] = bx(v2, k);
        }
#pragma unroll
        for (int i = 0; i < 4; ++i) {
            unsigned acc = Bt[i + 2] | Bt[i + 3] | Bt[i + 4] | Bt[i + 5] | Bt[i + 6];
            if (acc) uw |= 1u << (8 * i);
        }
    } else {
        for (int i = 0; i < 4; ++i) {
            int x = x0 + i;
            int y0 = y - RAD < 0 ? 0 : y - RAD, y1 = y + RAD >= HH ? HH - 1 : y + RAD;
            int xx0 = x - RAD < 0 ? 0 : x - RAD, xx1 = x + RAD >= WW ? WW - 1 : x + RAD;
            unsigned acc = 0;
            for (int yy = y0; yy <= y1; ++yy) {
                const uint8_t* row = m + yy * WW;
                for (int xx = xx0; xx <= xx1; ++xx) acc |= row[xx];
            }
            if (acc) uw |= 1u << (8 * i);
        }
    }
    *(unsigned*)(U + gid4) = uw;
}

// ---- 4-wide update (+optional hist): supp=U?0:S; M |= (supp==maxpool5(supp)) & ~U ----
template <int DOHIST>
__global__ void k_update4(const float* __restrict__ S, const uint8_t* __restrict__ U,
                          uint8_t* __restrict__ M, unsigned* __restrict__ hist) {
    int g = blockIdx.x * 256 + threadIdx.x;
    int gid4 = g * 4;
    int b = gid4 / HWp, p = gid4 - b * HWp;
    int y = p / WW, x0 = p - y * WW;
    const float* img = S + b * HWp;
    const uint8_t* u = U + b * HWp;
    float o4[4], c4[4];
    unsigned ub4[4];
    if (y >= RAD && y < HH - RAD && x0 >= 4 && x0 <= WW - 8) {
        float cm[12];
#pragma unroll
        for (int dy = 0; dy < 5; ++dy) {
            const float* sr = img + (y - 2 + dy) * WW + x0 - 4;
            const unsigned* ur = (const unsigned*)(u + (y - 2 + dy) * WW + x0 - 4);
            float4 fa = *(const float4*)sr;
            float4 fb = *(const float4*)(sr + 4);
            float4 fc = *(const float4*)(sr + 8);
            unsigned ua = ur[0], um = ur[1], uc = ur[2];
            float s[12] = {fa.x, fa.y, fa.z, fa.w, fb.x, fb.y, fb.z, fb.w,
                           fc.x, fc.y, fc.z, fc.w};
            if (dy == 2) {
                c4[0] = fb.x; c4[1] = fb.y; c4[2] = fb.z; c4[3] = fb.w;
                ub4[0] = bx(um, 0); ub4[1] = bx(um, 1);
                ub4[2] = bx(um, 2); ub4[3] = bx(um, 3);
            }
#pragma unroll
            for (int k = 0; k < 12; ++k) {
                unsigned mb = bx(k < 4 ? ua : (k < 8 ? um : uc), k & 3);
                float v = mb ? 0.f : s[k];
                cm[k] = (dy == 0) ? v : fmaxf(cm[k], v);
            }
        }
#pragma unroll
        for (int i = 0; i < 4; ++i)
            o4[i] = fmaxf(fmaxf(fmaxf(cm[i + 2], cm[i + 3]),
                                fmaxf(cm[i + 4], cm[i + 5])), cm[i + 6]);
    } else {
        for (int i = 0; i < 4; ++i) {
            int x = x0 + i;
            int y0 = y - RAD < 0 ? 0 : y - RAD, y1 = y + RAD >= HH ? HH - 1 : y + RAD;
            int xx0 = x - RAD < 0 ? 0 : x - RAD, xx1 = x + RAD >= WW ? WW - 1 : x + RAD;
            float mx = -1e30f;
            for (int yy = y0; yy <= y1; ++yy) {
                const float* row = img + yy * WW;
                const uint8_t* urow = u + yy * WW;
                for (int xx = xx0; xx <= xx1; ++xx) {
                    float v = urow[xx] ? 0.f : row[xx];
                    mx = fmaxf(mx, v);
                }
            }
            o4[i] = mx;
            c4[i] = img[y * WW + x];
            ub4[i] = u[y * WW + x];
        }
    }
    unsigned mw = *(unsigned*)(M + gid4);
#pragma unroll
    for (int i = 0; i < 4; ++i)
        if (!ub4[i] && c4[i] == o4[i]) mw |= 1u << (8 * i);
    *(unsigned*)(M + gid4) = mw;
    if (DOHIST) {
#pragma unroll
        for (int i = 0; i < 4; ++i) {
            int x = x0 + i;
            if (((mw >> (8 * i)) & 0xFF) && y >= RAD + 1 && y < HH - RAD &&
                x >= RAD + 1 && x < WW - RAD && c4[i] != 0.f) {
                unsigned bits = __float_as_uint(c4[i]);
                atomicAdd(&hist[b * NBINS + (bits >> 16)], 1u);
            }
        }
    }
}

// per-batch: threshold bin T s.t. count(bins > T) < TOPK <= count(bins >= T)
__global__ __launch_bounds__(1024) void k_scan(const unsigned* __restrict__ hist,
                                               int* __restrict__ Tbin) {
    __shared__ unsigned b0[1024], b1[1024];
    int b = blockIdx.x, t = threadIdx.x;
    const unsigned* h = hist + b * NBINS;
    int base = NBINS - (t + 1) * 64;
    unsigned s = 0;
    for (int i = 0; i < 64; ++i) s += h[base + i];
    b0[t] = s;
    __syncthreads();
    unsigned* src = b0; unsigned* dst = b1;
    for (int off = 1; off < 1024; off <<= 1) {
        unsigned v = src[t];
        if (t >= off) v += src[t - off];
        dst[t] = v;
        __syncthreads();
        unsigned* tmp = src; src = dst; dst = tmp;
    }
    unsigned incl = src[t];
    unsigned excl = incl - s;
    unsigned total = src[1023];
    const unsigned K = TOPK;
    if (excl < K && K <= incl) {
        unsigned run = excl;
        for (int i = 0; i < 64; ++i) {
            int bin = NBINS - 1 - t * 64 - i;
            unsigned c = h[bin];
            if (run < K && K <= run + c) { Tbin[b] = bin; break; }
            run += c;
        }
    }
    if (t == 1023 && total < K) Tbin[b] = 0;
}

// block-aggregated compaction
__global__ void k_compact(const float* __restrict__ S, const uint8_t* __restrict__ M,
                          const int* __restrict__ Tbin,
                          unsigned* __restrict__ cnt, unsigned long long* __restrict__ cand) {
    __shared__ unsigned lcnt, lbase;
    int gid = blockIdx.x * 256 + threadIdx.x;
    int b = gid / HWp, p = gid - b * HWp;
    int y = p / WW, x = p - y * WW;
    if (threadIdx.x == 0) lcnt = 0;
    __syncthreads();
    bool win = false;
    unsigned mypos = 0;
    unsigned long long key = 0;
    if (M[gid] && y >= RAD + 1 && y < HH - RAD && x >= RAD + 1 && x < WW - RAD) {
        float v = S[gid];
        if (v != 0.f) {
            unsigned bits = __float_as_uint(v);
            if ((int)(bits >> 16) >= Tbin[b]) {
                mypos = atomicAdd(&lcnt, 1u);
                key = ((unsigned long long)bits << 32) | (unsigned)(~(unsigned)p);
                win = true;
            }
        }
    }
    __syncthreads();
    if (threadIdx.x == 0 && lcnt)
        lbase = atomicAdd(&cnt[b * CNT_STRIDE], lcnt);
    __syncthreads();
    if (win) {
        unsigned pos = lbase + mypos;
        if (pos < CAND_CAP) cand[b * CAND_CAP + pos] = key;
    }
}

// one block per batch: bitonic-sort 8192 keys descending, emit top 4096 indices
__global__ __launch_bounds__(1024) void k_sort(const unsigned* __restrict__ cnt,
                                               const unsigned long long* __restrict__ cand,
                                               int* __restrict__ kp) {
    __shared__ unsigned long long keys[CAND_CAP];
    int b = blockIdx.x, t = threadIdx.x;
    unsigned nr = cnt[b * CNT_STRIDE];
    if (nr > CAND_CAP) nr = CAND_CAP;
    for (int i = t; i < CAND_CAP; i += 1024)
        keys[i] = (i < (int)nr) ? cand[b * CAND_CAP + i] : 0ull;
    __syncthreads();
    for (int k = 2; k <= CAND_CAP; k <<= 1) {
        for (int j = k >> 1; j > 0; j >>= 1) {
            for (int i = t; i < CAND_CAP; i += 1024) {
                int ixj = i ^ j;
                if (ixj > i) {
                    bool asc = (i & k) != 0;
                    unsigned long long a = keys[i], c = keys[ixj];
                    bool sw = asc ? (a > c) : (a < c);
                    if (sw) { keys[i] = c; keys[ixj] = a; }
                }
            }
            __syncthreads();
        }
    }
    for (int i = t; i < TOPK; i += 1024) {
        unsigned long long key = keys[i];
        int idx;
        if (key != 0ull) idx = (int)(~(unsigned)(key & 0xFFFFFFFFull));
        else             idx = i - (int)nr;
        kp[b * TOPK + i] = idx;
    }
}

// per-keypoint: softmax soft-argmax + disp + normalized coords + bilinear score
__global__ void k_kp(const float* __restrict__ S, const int* __restrict__ kp,
                     float* __restrict__ out) {
    int g = blockIdx.x * blockDim.x + threadIdx.x;
    if (g >= BN * TOPK) return;
    int b = g >> 12;
    int idx = kp[g];
    int y = idx / WW, x = idx - y * WW;
    const float* img = S + b * HWp;
    float ps[25];
#pragma unroll
    for (int di = 0; di < 5; ++di) {
#pragma unroll
        for (int dj = 0; dj < 5; ++dj) {
            int yy = y + di - RAD, xx = x + dj - RAD;
            bool ok = (yy >= 0) && (yy < HH) && (xx >= 0) && (xx < WW);
            ps[di * 5 + dj] = ok ? img[yy * WW + xx] : 0.f;
        }
    }
    float mx = ps[0];
#pragma unroll
    for (int p = 1; p < 25; ++p) mx = fmaxf(mx, ps[p]);
    float ssum = 0.f, sx = 0.f, sy = 0.f, sg2 = 0.f;
#pragma unroll
    for (int p = 0; p < 25; ++p) {
        float dx = (float)(p % 5) - 2.f;
        float dy = (float)(p / 5) - 2.f;
        float e = expf((ps[p] - mx) / 0.1f);
        ssum += e;
        sx += e * dx;
        sy += e * dy;
        sg2 += e * (dx * dx + dy * dy);
    }
    float xr = sx / ssum, yr = sy / ssum;
    float disp = (sg2 - 2.f * (xr * sx + yr * sy) + (xr * xr + yr * yr) * ssum)
                 / (4.f * ssum);
    float kxn = ((float)x + xr) / (float)(WW - 1) * 2.f - 1.f;
    float kyn = ((float)y + yr) / (float)(HH - 1) * 2.f - 1.f;
    out[2 * g]     = kxn;
    out[2 * g + 1] = kyn;
    float px = (kxn + 1.f) * 0.5f * (float)(WW - 1);
    float py = (kyn + 1.f) * 0.5f * (float)(HH - 1);
    float x0 = floorf(px), y0f = floorf(py);
    float wx = px - x0, wy = py - y0f;
    int x0i = (int)fminf(fmaxf(x0, 0.f), (float)(WW - 1));
    int x1i = (int)fminf(fmaxf(x0 + 1.f, 0.f), (float)(WW - 1));
    int y0i = (int)fminf(fmaxf(y0f, 0.f), (float)(HH - 1));
    int y1i = (int)fminf(fmaxf(y0f + 1.f, 0.f), (float)(HH - 1));
    float v00 = img[y0i * WW + x0i], v01 = img[y0i * WW + x1i];
    float v10 = img[y1i * WW + x0i], v11 = img[y1i * WW + x1i];
    float sc = v00 * (1.f - wx) * (1.f - wy) + v01 * wx * (1.f - wy)
             + v10 * (1.f - wx) * wy + v11 * wx * wy;
    out[BN * TOPK * 2 + g] = sc;
    out[BN * TOPK * 3 + g] = disp;
}

extern "C" void kernel_launch(void* const* d_in, const int* in_sizes, int n_in,
                              void* d_out, int out_size, void* d_ws, size_t ws_size,
                              hipStream_t stream) {
    const float* S = (const float*)d_in[0];
    float* out = (float*)d_out;
    char* ws = (char*)d_ws;

    uint8_t*            M     = (uint8_t*)(ws + OFF_M);
    uint8_t*            U     = (uint8_t*)(ws + OFF_U);
    unsigned*           hist  = (unsigned*)(ws + OFF_HIST);
    unsigned*           cnt   = (unsigned*)(ws + OFF_CNT);
    int*                Tbin  = (int*)(ws + OFF_TBIN);
    unsigned long long* cand  = (unsigned long long*)(ws + OFF_CAND);
    int*                kpidx = (int*)(ws + OFF_KPIDX);

    int zwords = (BN * NBINS * 4 + 1024) / 4;
    k_zero<<<(zwords + 255) / 256, 256, 0, stream>>>(hist, zwords);

    int nblk4 = (NPIX / 4 + 255) / 256;   // 4 pixels per thread
    int nblk  = (NPIX + 255) / 256;
    k_mask4<<<nblk4, 256, 0, stream>>>(S, M);
    k_dilate4<<<nblk4, 256, 0, stream>>>(M, U);
    k_update4<0><<<nblk4, 256, 0, stream>>>(S, U, M, hist);
    k_dilate4<<<nblk4, 256, 0, stream>>>(M, U);
    k_update4<1><<<nblk4, 256, 0, stream>>>(S, U, M, hist);
    k_scan<<<BN, 1024, 0, stream>>>(hist, Tbin);
    k_compact<<<nblk, 256, 0, stream>>>(S, M, Tbin, cnt, cand);
    k_sort<<<BN, 1024, 0, stream>>>(cnt, cand, kpidx);
    k_kp<<<(BN * TOPK + 255) / 256, 256, 0, stream>>>(S, kpidx, out);
}

// Round 11
// 439.179 us; speedup vs baseline: 2.1524x; 1.0911x over previous
//
#include <hip/hip_runtime.h>
#include <cstdint>

#define BN 8
#define HH 512
#define WW 640
#define HWp (HH*WW)
#define NPIX (BN*HWp)
#define RAD 2
#define TOPK 4096
#define NBINS 65536
#define CAND_CAP 8192

// workspace layout (bytes)
#define OFF_M     0
#define OFF_U     (OFF_M + NPIX)
#define OFF_HIST  (OFF_U + NPIX)
#define OFF_CNT   (OFF_HIST + BN*NBINS*4)
#define OFF_TBIN  (OFF_CNT + 1024)
#define OFF_CAND  (OFF_TBIN + 128)
#define OFF_KPIDX (OFF_CAND + BN*CAND_CAP*8)

#define CNT_STRIDE 32   // uints; 128 bytes between per-batch counters

// fused-NMS tiling
#define TILE 48
#define HALO 10
#define STG  68          // TILE + 2*HALO
#define LSTR 72          // LDS row stride (floats)
#define GTX  14          // ceil(640/48)
#define GTY  11          // ceil(512/48)

__global__ void k_zero(unsigned* __restrict__ p, int n) {
    int i = blockIdx.x * blockDim.x + threadIdx.x;
    if (i < n) p[i] = 0u;
}

// ---- one block = one 48x48 output tile: full simple_nms (2 iters) + hist ----
__global__ __launch_bounds__(256) void k_nms_fused(const float* __restrict__ S,
                                                   uint8_t* __restrict__ M,
                                                   unsigned* __restrict__ hist) {
    __shared__ float   sm [STG][LSTR];
    __shared__ float   tmp[STG][LSTR];
    __shared__ uint8_t mbuf[STG][LSTR];
    __shared__ uint8_t ubuf[STG][LSTR];

    int bid = blockIdx.x;
    int b   = bid / (GTX * GTY);
    int t   = bid - b * (GTX * GTY);
    int tyy = t / GTX, txx = t - tyy * GTX;
    int oy = tyy * TILE - HALO;
    int ox = txx * TILE - HALO;
    const float* img = S + b * HWp;
    int tid = threadIdx.x;
    const float NEG = -__builtin_inff();

    // stage S (OOB = -inf, matching SAME max-pool padding)
    for (int idx = tid; idx < STG * STG; idx += 256) {
        int i = idx / STG, j = idx - i * STG;
        int Y = oy + i, X = ox + j;
        sm[i][j] = (Y >= 0 && Y < HH && X >= 0 && X < WW) ? img[Y * WW + X] : NEG;
    }
    __syncthreads();

    // ---- pass 1: mask = (s == maxpool5(s)), centers [2,65]^2 ----
    for (int idx = tid; idx < 64 * STG; idx += 256) {          // vertical
        int r = idx / STG, j = idx - r * STG;
        int ci = r + 2;
        float m0 = fmaxf(fmaxf(sm[ci-2][j], sm[ci-1][j]),
                         fmaxf(sm[ci][j],   sm[ci+1][j]));
        tmp[ci][j] = fmaxf(m0, sm[ci+2][j]);
    }
    __syncthreads();
    for (int idx = tid; idx < 64 * 64; idx += 256) {           // horizontal
        int r = idx >> 6, c = idx & 63;
        int ci = r + 2, cj = c + 2;
        float mx = fmaxf(fmaxf(tmp[ci][cj-2], tmp[ci][cj-1]),
                         fmaxf(fmaxf(tmp[ci][cj], tmp[ci][cj+1]), tmp[ci][cj+2]));
        int Y = oy + ci, X = ox + cj;
        bool valid = (Y >= 0 && Y < HH && X >= 0 && X < WW);
        mbuf[ci][cj] = (valid && sm[ci][cj] == mx) ? (uint8_t)1 : (uint8_t)0;
    }
    __syncthreads();

    // ---- pass 2: u1 = dilate5(m), centers [4,63]^2 ----
    for (int idx = tid; idx < 60 * STG; idx += 256) {
        int r = idx / STG, j = idx - r * STG;
        int ci = r + 4;
        int acc = mbuf[ci-2][j] | mbuf[ci-1][j] | mbuf[ci][j]
                | mbuf[ci+1][j] | mbuf[ci+2][j];
        tmp[ci][j] = (float)acc;
    }
    __syncthreads();
    for (int idx = tid; idx < 60 * 60; idx += 256) {
        int r = idx / 60, c = idx - r * 60;
        int ci = r + 4, cj = c + 4;
        float mx = fmaxf(fmaxf(tmp[ci][cj-2], tmp[ci][cj-1]),
                         fmaxf(fmaxf(tmp[ci][cj], tmp[ci][cj+1]), tmp[ci][cj+2]));
        ubuf[ci][cj] = (mx > 0.f) ? (uint8_t)1 : (uint8_t)0;
    }
    __syncthreads();

    // ---- pass 3: update1: m |= (supp==maxpool5(supp)) & ~u1, centers [6,61]^2 ----
    for (int idx = tid; idx < 56 * STG; idx += 256) {
        int r = idx / STG, j = idx - r * STG;
        int ci = r + 6;
        float v0 = ubuf[ci-2][j] ? 0.f : sm[ci-2][j];
        float v1 = ubuf[ci-1][j] ? 0.f : sm[ci-1][j];
        float v2 = ubuf[ci  ][j] ? 0.f : sm[ci  ][j];
        float v3 = ubuf[ci+1][j] ? 0.f : sm[ci+1][j];
        float v4 = ubuf[ci+2][j] ? 0.f : sm[ci+2][j];
        tmp[ci][j] = fmaxf(fmaxf(fmaxf(v0, v1), fmaxf(v2, v3)), v4);
    }
    __syncthreads();
    for (int idx = tid; idx < 56 * 56; idx += 256) {
        int r = idx / 56, c = idx - r * 56;
        int ci = r + 6, cj = c + 6;
        float mx = fmaxf(fmaxf(tmp[ci][cj-2], tmp[ci][cj-1]),
                         fmaxf(fmaxf(tmp[ci][cj], tmp[ci][cj+1]), tmp[ci][cj+2]));
        uint8_t u = ubuf[ci][cj];
        float vc = u ? 0.f : sm[ci][cj];
        int Y = oy + ci, X = ox + cj;
        bool valid = (Y >= 0 && Y < HH && X >= 0 && X < WW);
        if (valid && !u && vc == mx) mbuf[ci][cj] = 1;
    }
    __syncthreads();

    // ---- pass 4: u2 = dilate5(m2), centers [8,59]^2 ----
    for (int idx = tid; idx < 52 * STG; idx += 256) {
        int r = idx / STG, j = idx - r * STG;
        int ci = r + 8;
        int acc = mbuf[ci-2][j] | mbuf[ci-1][j] | mbuf[ci][j]
                | mbuf[ci+1][j] | mbuf[ci+2][j];
        tmp[ci][j] = (float)acc;
    }
    __syncthreads();
    for (int idx = tid; idx < 52 * 52; idx += 256) {
        int r = idx / 52, c = idx - r * 52;
        int ci = r + 8, cj = c + 8;
        float mx = fmaxf(fmaxf(tmp[ci][cj-2], tmp[ci][cj-1]),
                         fmaxf(fmaxf(tmp[ci][cj], tmp[ci][cj+1]), tmp[ci][cj+2]));
        ubuf[ci][cj] = (mx > 0.f) ? (uint8_t)1 : (uint8_t)0;
    }
    __syncthreads();

    // ---- pass 5: update2 + emit M + hist, centers [10,57]^2 (48x48 output) ----
    for (int idx = tid; idx < 48 * STG; idx += 256) {
        int r = idx / STG, j = idx - r * STG;
        int ci = r + 10;
        float v0 = ubuf[ci-2][j] ? 0.f : sm[ci-2][j];
        float v1 = ubuf[ci-1][j] ? 0.f : sm[ci-1][j];
        float v2 = ubuf[ci  ][j] ? 0.f : sm[ci  ][j];
        float v3 = ubuf[ci+1][j] ? 0.f : sm[ci+1][j];
        float v4 = ubuf[ci+2][j] ? 0.f : sm[ci+2][j];
        tmp[ci][j] = fmaxf(fmaxf(fmaxf(v0, v1), fmaxf(v2, v3)), v4);
    }
    __syncthreads();
    for (int idx = tid; idx < 48 * 48; idx += 256) {
        int r = idx / 48, c = idx - r * 48;
        int ci = r + 10, cj = c + 10;
        int Y = oy + ci, X = ox + cj;
        if (Y >= HH || X >= WW) continue;          // partial edge tiles (Y,X >= 10-halo >= 0)
        float mx = fmaxf(fmaxf(tmp[ci][cj-2], tmp[ci][cj-1]),
                         fmaxf(fmaxf(tmp[ci][cj], tmp[ci][cj+1]), tmp[ci][cj+2]));
        uint8_t u = ubuf[ci][cj];
        float cv = sm[ci][cj];
        float vc = u ? 0.f : cv;
        uint8_t m3 = mbuf[ci][cj];
        if (!u && vc == mx) m3 = 1;
        M[b * HWp + Y * WW + X] = m3;
        if (m3 && Y >= RAD + 1 && Y < HH - RAD && X >= RAD + 1 && X < WW - RAD
            && cv != 0.f) {
            unsigned bits = __float_as_uint(cv);
            atomicAdd(&hist[b * NBINS + (bits >> 16)], 1u);
        }
    }
}

// per-batch: threshold bin T s.t. count(bins > T) < TOPK <= count(bins >= T)
__global__ __launch_bounds__(1024) void k_scan(const unsigned* __restrict__ hist,
                                               int* __restrict__ Tbin) {
    __shared__ unsigned b0[1024], b1[1024];
    int b = blockIdx.x, t = threadIdx.x;
    const unsigned* h = hist + b * NBINS;
    int base = NBINS - (t + 1) * 64;
    unsigned s = 0;
    for (int i = 0; i < 64; ++i) s += h[base + i];
    b0[t] = s;
    __syncthreads();
    unsigned* src = b0; unsigned* dst = b1;
    for (int off = 1; off < 1024; off <<= 1) {
        unsigned v = src[t];
        if (t >= off) v += src[t - off];
        dst[t] = v;
        __syncthreads();
        unsigned* tmp2 = src; src = dst; dst = tmp2;
    }
    unsigned incl = src[t];
    unsigned excl = incl - s;
    unsigned total = src[1023];
    const unsigned K = TOPK;
    if (excl < K && K <= incl) {
        unsigned run = excl;
        for (int i = 0; i < 64; ++i) {
            int bin = NBINS - 1 - t * 64 - i;
            unsigned c = h[bin];
            if (run < K && K <= run + c) { Tbin[b] = bin; break; }
            run += c;
        }
    }
    if (t == 1023 && total < K) Tbin[b] = 0;
}

// block-aggregated compaction
__global__ void k_compact(const float* __restrict__ S, const uint8_t* __restrict__ M,
                          const int* __restrict__ Tbin,
                          unsigned* __restrict__ cnt, unsigned long long* __restrict__ cand) {
    __shared__ unsigned lcnt, lbase;
    int gid = blockIdx.x * 256 + threadIdx.x;
    int b = gid / HWp, p = gid - b * HWp;
    int y = p / WW, x = p - y * WW;
    if (threadIdx.x == 0) lcnt = 0;
    __syncthreads();
    bool win = false;
    unsigned mypos = 0;
    unsigned long long key = 0;
    if (M[gid] && y >= RAD + 1 && y < HH - RAD && x >= RAD + 1 && x < WW - RAD) {
        float v = S[gid];
        if (v != 0.f) {
            unsigned bits = __float_as_uint(v);
            if ((int)(bits >> 16) >= Tbin[b]) {
                mypos = atomicAdd(&lcnt, 1u);
                key = ((unsigned long long)bits << 32) | (unsigned)(~(unsigned)p);
                win = true;
            }
        }
    }
    __syncthreads();
    if (threadIdx.x == 0 && lcnt)
        lbase = atomicAdd(&cnt[b * CNT_STRIDE], lcnt);
    __syncthreads();
    if (win) {
        unsigned pos = lbase + mypos;
        if (pos < CAND_CAP) cand[b * CAND_CAP + pos] = key;
    }
}

// one block per batch: bitonic-sort 8192 keys descending, emit top 4096 indices
__global__ __launch_bounds__(1024) void k_sort(const unsigned* __restrict__ cnt,
                                               const unsigned long long* __restrict__ cand,
                                               int* __restrict__ kp) {
    __shared__ unsigned long long keys[CAND_CAP];
    int b = blockIdx.x, t = threadIdx.x;
    unsigned nr = cnt[b * CNT_STRIDE];
    if (nr > CAND_CAP) nr = CAND_CAP;
    for (int i = t; i < CAND_CAP; i += 1024)
        keys[i] = (i < (int)nr) ? cand[b * CAND_CAP + i] : 0ull;
    __syncthreads();
    for (int k = 2; k <= CAND_CAP; k <<= 1) {
        for (int j = k >> 1; j > 0; j >>= 1) {
            for (int i = t; i < CAND_CAP; i += 1024) {
                int ixj = i ^ j;
                if (ixj > i) {
                    bool asc = (i & k) != 0;
                    unsigned long long a = keys[i], c = keys[ixj];
                    bool sw = asc ? (a > c) : (a < c);
                    if (sw) { keys[i] = c; keys[ixj] = a; }
                }
            }
            __syncthreads();
        }
    }
    for (int i = t; i < TOPK; i += 1024) {
        unsigned long long key = keys[i];
        int idx;
        if (key != 0ull) idx = (int)(~(unsigned)(key & 0xFFFFFFFFull));
        else             idx = i - (int)nr;
        kp[b * TOPK + i] = idx;
    }
}

// per-keypoint: softmax soft-argmax + disp + normalized coords + bilinear score
__global__ void k_kp(const float* __restrict__ S, const int* __restrict__ kp,
                     float* __restrict__ out) {
    int g = blockIdx.x * blockDim.x + threadIdx.x;
    if (g >= BN * TOPK) return;
    int b = g >> 12;
    int idx = kp[g];
    int y = idx / WW, x = idx - y * WW;
    const float* img = S + b * HWp;
    float ps[25];
#pragma unroll
    for (int di = 0; di < 5; ++di) {
#pragma unroll
        for (int dj = 0; dj < 5; ++dj) {
            int yy = y + di - RAD, xx = x + dj - RAD;
            bool ok = (yy >= 0) && (yy < HH) && (xx >= 0) && (xx < WW);
            ps[di * 5 + dj] = ok ? img[yy * WW + xx] : 0.f;
        }
    }
    float mx = ps[0];
#pragma unroll
    for (int p = 1; p < 25; ++p) mx = fmaxf(mx, ps[p]);
    float ssum = 0.f, sx = 0.f, sy = 0.f, sg2 = 0.f;
#pragma unroll
    for (int p = 0; p < 25; ++p) {
        float dx = (float)(p % 5) - 2.f;
        float dy = (float)(p / 5) - 2.f;
        float e = expf((ps[p] - mx) / 0.1f);
        ssum += e;
        sx += e * dx;
        sy += e * dy;
        sg2 += e * (dx * dx + dy * dy);
    }
    float xr = sx / ssum, yr = sy / ssum;
    float disp = (sg2 - 2.f * (xr * sx + yr * sy) + (xr * xr + yr * yr) * ssum)
                 / (4.f * ssum);
    float kxn = ((float)x + xr) / (float)(WW - 1) * 2.f - 1.f;
    float kyn = ((float)y + yr) / (float)(HH - 1) * 2.f - 1.f;
    out[2 * g]     = kxn;
    out[2 * g + 1] = kyn;
    float px = (kxn + 1.f) * 0.5f * (float)(WW - 1);
    float py = (kyn + 1.f) * 0.5f * (float)(HH - 1);
    float x0 = floorf(px), y0f = floorf(py);
    float wx = px - x0, wy = py - y0f;
    int x0i = (int)fminf(fmaxf(x0, 0.f), (float)(WW - 1));
    int x1i = (int)fminf(fmaxf(x0 + 1.f, 0.f), (float)(WW - 1));
    int y0i = (int)fminf(fmaxf(y0f, 0.f), (float)(HH - 1));
    int y1i = (int)fminf(fmaxf(y0f + 1.f, 0.f), (float)(HH - 1));
    float v00 = img[y0i * WW + x0i], v01 = img[y0i * WW + x1i];
    float v10 = img[y1i * WW + x0i], v11 = img[y1i * WW + x1i];
    float sc = v00 * (1.f - wx) * (1.f - wy) + v01 * wx * (1.f - wy)
             + v10 * (1.f - wx) * wy + v11 * wx * wy;
    out[BN * TOPK * 2 + g] = sc;
    out[BN * TOPK * 3 + g] = disp;
}

extern "C" void kernel_launch(void* const* d_in, const int* in_sizes, int n_in,
                              void* d_out, int out_size, void* d_ws, size_t ws_size,
                              hipStream_t stream) {
    const float* S = (const float*)d_in[0];
    float* out = (float*)d_out;
    char* ws = (char*)d_ws;

    uint8_t*            M     = (uint8_t*)(ws + OFF_M);
    unsigned*           hist  = (unsigned*)(ws + OFF_HIST);
    unsigned*           cnt   = (unsigned*)(ws + OFF_CNT);
    int*                Tbin  = (int*)(ws + OFF_TBIN);
    unsigned long long* cand  = (unsigned long long*)(ws + OFF_CAND);
    int*                kpidx = (int*)(ws + OFF_KPIDX);

    int zwords = (BN * NBINS * 4 + 1024) / 4;
    k_zero<<<(zwords + 255) / 256, 256, 0, stream>>>(hist, zwords);

    k_nms_fused<<<BN * GTX * GTY, 256, 0, stream>>>(S, M, hist);

    int nblk = (NPIX + 255) / 256;
    k_scan<<<BN, 1024, 0, stream>>>(hist, Tbin);
    k_compact<<<nblk, 256, 0, stream>>>(S, M, Tbin, cnt, cand);
    k_sort<<<BN, 1024, 0, stream>>>(cnt, cand, kpidx);
    k_kp<<<(BN * TOPK + 255) / 256, 256, 0, stream>>>(S, kpidx, out);
}

// Round 12
// 424.825 us; speedup vs baseline: 2.2251x; 1.0338x over previous
//
#include <hip/hip_runtime.h>
#include <cstdint>

#define BN 8
#define HH 512
#define WW 640
#define HWp (HH*WW)
#define NPIX (BN*HWp)
#define RAD 2
#define TOPK 4096
#define NBINS 65536
#define CAND_CAP 8192

// workspace layout (bytes)
#define OFF_M     0
#define OFF_U     (OFF_M + NPIX)
#define OFF_HIST  (OFF_U + NPIX)
#define OFF_CNT   (OFF_HIST + BN*NBINS*4)
#define OFF_TBIN  (OFF_CNT + 1024)
#define OFF_CAND  (OFF_TBIN + 128)
#define OFF_KPIDX (OFF_CAND + BN*CAND_CAP*8)

#define CNT_STRIDE 32   // uints; 128 bytes between per-batch counters

// fused-NMS tiling: 32x32 output tile, halo 10 -> 28.4 KB LDS, 5 blocks/CU
#define TILE 32
#define HALO 10
#define STG  52          // TILE + 2*HALO
#define LSTR 56          // LDS row stride (floats)
#define GTX  20          // 640/32 exact
#define GTY  16          // 512/32 exact

__global__ void k_zero(unsigned* __restrict__ p, int n) {
    int i = blockIdx.x * blockDim.x + threadIdx.x;
    if (i < n) p[i] = 0u;
}

// ---- one block = one 32x32 output tile: full simple_nms (2 iters) + hist ----
__global__ __launch_bounds__(256) void k_nms_fused(const float* __restrict__ S,
                                                   uint8_t* __restrict__ M,
                                                   unsigned* __restrict__ hist) {
    __shared__ float   sm [STG][LSTR];
    __shared__ float   tmp[STG][LSTR];
    __shared__ uint8_t mbuf[STG][LSTR];
    __shared__ uint8_t ubuf[STG][LSTR];

    int bid = blockIdx.x;
    int b   = bid / (GTX * GTY);
    int t   = bid - b * (GTX * GTY);
    int tyy = t / GTX, txx = t - tyy * GTX;
    int oy = tyy * TILE - HALO;
    int ox = txx * TILE - HALO;
    const float* img = S + b * HWp;
    int tid = threadIdx.x;
    const float NEG = -__builtin_inff();

    // stage S (OOB = -inf, matching SAME max-pool padding)
    for (int idx = tid; idx < STG * STG; idx += 256) {
        int i = idx / STG, j = idx - i * STG;
        int Y = oy + i, X = ox + j;
        sm[i][j] = (Y >= 0 && Y < HH && X >= 0 && X < WW) ? img[Y * WW + X] : NEG;
    }
    __syncthreads();

    // ---- pass 1: mask = (s == maxpool5(s)), centers [2,49]^2 (48 wide) ----
    for (int idx = tid; idx < 48 * STG; idx += 256) {          // vertical
        int r = idx / STG, j = idx - r * STG;
        int ci = r + 2;
        float m0 = fmaxf(fmaxf(sm[ci-2][j], sm[ci-1][j]),
                         fmaxf(sm[ci][j],   sm[ci+1][j]));
        tmp[ci][j] = fmaxf(m0, sm[ci+2][j]);
    }
    __syncthreads();
    for (int idx = tid; idx < 48 * 48; idx += 256) {           // horizontal
        int r = idx / 48, c = idx - r * 48;
        int ci = r + 2, cj = c + 2;
        float mx = fmaxf(fmaxf(tmp[ci][cj-2], tmp[ci][cj-1]),
                         fmaxf(fmaxf(tmp[ci][cj], tmp[ci][cj+1]), tmp[ci][cj+2]));
        int Y = oy + ci, X = ox + cj;
        bool valid = (Y >= 0 && Y < HH && X >= 0 && X < WW);
        mbuf[ci][cj] = (valid && sm[ci][cj] == mx) ? (uint8_t)1 : (uint8_t)0;
    }
    __syncthreads();

    // ---- pass 2: u1 = dilate5(m), centers [4,47]^2 (44 wide) ----
    for (int idx = tid; idx < 44 * STG; idx += 256) {
        int r = idx / STG, j = idx - r * STG;
        int ci = r + 4;
        int acc = mbuf[ci-2][j] | mbuf[ci-1][j] | mbuf[ci][j]
                | mbuf[ci+1][j] | mbuf[ci+2][j];
        tmp[ci][j] = (float)acc;
    }
    __syncthreads();
    for (int idx = tid; idx < 44 * 44; idx += 256) {
        int r = idx / 44, c = idx - r * 44;
        int ci = r + 4, cj = c + 4;
        float mx = fmaxf(fmaxf(tmp[ci][cj-2], tmp[ci][cj-1]),
                         fmaxf(fmaxf(tmp[ci][cj], tmp[ci][cj+1]), tmp[ci][cj+2]));
        ubuf[ci][cj] = (mx > 0.f) ? (uint8_t)1 : (uint8_t)0;
    }
    __syncthreads();

    // ---- pass 3: update1: m |= (supp==maxpool5(supp)) & ~u1, centers [6,45]^2 ----
    for (int idx = tid; idx < 40 * STG; idx += 256) {
        int r = idx / STG, j = idx - r * STG;
        int ci = r + 6;
        float v0 = ubuf[ci-2][j] ? 0.f : sm[ci-2][j];
        float v1 = ubuf[ci-1][j] ? 0.f : sm[ci-1][j];
        float v2 = ubuf[ci  ][j] ? 0.f : sm[ci  ][j];
        float v3 = ubuf[ci+1][j] ? 0.f : sm[ci+1][j];
        float v4 = ubuf[ci+2][j] ? 0.f : sm[ci+2][j];
        tmp[ci][j] = fmaxf(fmaxf(fmaxf(v0, v1), fmaxf(v2, v3)), v4);
    }
    __syncthreads();
    for (int idx = tid; idx < 40 * 40; idx += 256) {
        int r = idx / 40, c = idx - r * 40;
        int ci = r + 6, cj = c + 6;
        float mx = fmaxf(fmaxf(tmp[ci][cj-2], tmp[ci][cj-1]),
                         fmaxf(fmaxf(tmp[ci][cj], tmp[ci][cj+1]), tmp[ci][cj+2]));
        uint8_t u = ubuf[ci][cj];
        float vc = u ? 0.f : sm[ci][cj];
        int Y = oy + ci, X = ox + cj;
        bool valid = (Y >= 0 && Y < HH && X >= 0 && X < WW);
        if (valid && !u && vc == mx) mbuf[ci][cj] = 1;
    }
    __syncthreads();

    // ---- pass 4: u2 = dilate5(m2), centers [8,43]^2 ----
    for (int idx = tid; idx < 36 * STG; idx += 256) {
        int r = idx / STG, j = idx - r * STG;
        int ci = r + 8;
        int acc = mbuf[ci-2][j] | mbuf[ci-1][j] | mbuf[ci][j]
                | mbuf[ci+1][j] | mbuf[ci+2][j];
        tmp[ci][j] = (float)acc;
    }
    __syncthreads();
    for (int idx = tid; idx < 36 * 36; idx += 256) {
        int r = idx / 36, c = idx - r * 36;
        int ci = r + 8, cj = c + 8;
        float mx = fmaxf(fmaxf(tmp[ci][cj-2], tmp[ci][cj-1]),
                         fmaxf(fmaxf(tmp[ci][cj], tmp[ci][cj+1]), tmp[ci][cj+2]));
        ubuf[ci][cj] = (mx > 0.f) ? (uint8_t)1 : (uint8_t)0;
    }
    __syncthreads();

    // ---- pass 5: update2 + emit M + hist, centers [10,41]^2 (32x32 output) ----
    for (int idx = tid; idx < 32 * STG; idx += 256) {
        int r = idx / STG, j = idx - r * STG;
        int ci = r + 10;
        float v0 = ubuf[ci-2][j] ? 0.f : sm[ci-2][j];
        float v1 = ubuf[ci-1][j] ? 0.f : sm[ci-1][j];
        float v2 = ubuf[ci  ][j] ? 0.f : sm[ci  ][j];
        float v3 = ubuf[ci+1][j] ? 0.f : sm[ci+1][j];
        float v4 = ubuf[ci+2][j] ? 0.f : sm[ci+2][j];
        tmp[ci][j] = fmaxf(fmaxf(fmaxf(v0, v1), fmaxf(v2, v3)), v4);
    }
    __syncthreads();
    for (int idx = tid; idx < 32 * 32; idx += 256) {
        int r = idx >> 5, c = idx & 31;
        int ci = r + 10, cj = c + 10;
        int Y = oy + ci, X = ox + cj;
        if (Y >= HH || X >= WW) continue;
        float mx = fmaxf(fmaxf(tmp[ci][cj-2], tmp[ci][cj-1]),
                         fmaxf(fmaxf(tmp[ci][cj], tmp[ci][cj+1]), tmp[ci][cj+2]));
        uint8_t u = ubuf[ci][cj];
        float cv = sm[ci][cj];
        float vc = u ? 0.f : cv;
        uint8_t m3 = mbuf[ci][cj];
        if (!u && vc == mx) m3 = 1;
        M[b * HWp + Y * WW + X] = m3;
        if (m3 && Y >= RAD + 1 && Y < HH - RAD && X >= RAD + 1 && X < WW - RAD
            && cv != 0.f) {
            unsigned bits = __float_as_uint(cv);
            atomicAdd(&hist[b * NBINS + (bits >> 16)], 1u);
        }
    }
}

// per-batch: threshold bin T s.t. count(bins > T) < TOPK <= count(bins >= T)
__global__ __launch_bounds__(1024) void k_scan(const unsigned* __restrict__ hist,
                                               int* __restrict__ Tbin) {
    __shared__ unsigned b0[1024], b1[1024];
    int b = blockIdx.x, t = threadIdx.x;
    const unsigned* h = hist + b * NBINS;
    int base = NBINS - (t + 1) * 64;
    unsigned s = 0;
    for (int i = 0; i < 64; ++i) s += h[base + i];
    b0[t] = s;
    __syncthreads();
    unsigned* src = b0; unsigned* dst = b1;
    for (int off = 1; off < 1024; off <<= 1) {
        unsigned v = src[t];
        if (t >= off) v += src[t - off];
        dst[t] = v;
        __syncthreads();
        unsigned* tmp2 = src; src = dst; dst = tmp2;
    }
    unsigned incl = src[t];
    unsigned excl = incl - s;
    unsigned total = src[1023];
    const unsigned K = TOPK;
    if (excl < K && K <= incl) {
        unsigned run = excl;
        for (int i = 0; i < 64; ++i) {
            int bin = NBINS - 1 - t * 64 - i;
            unsigned c = h[bin];
            if (run < K && K <= run + c) { Tbin[b] = bin; break; }
            run += c;
        }
    }
    if (t == 1023 && total < K) Tbin[b] = 0;
}

// block-aggregated compaction
__global__ void k_compact(const float* __restrict__ S, const uint8_t* __restrict__ M,
                          const int* __restrict__ Tbin,
                          unsigned* __restrict__ cnt, unsigned long long* __restrict__ cand) {
    __shared__ unsigned lcnt, lbase;
    int gid = blockIdx.x * 256 + threadIdx.x;
    int b = gid / HWp, p = gid - b * HWp;
    int y = p / WW, x = p - y * WW;
    if (threadIdx.x == 0) lcnt = 0;
    __syncthreads();
    bool win = false;
    unsigned mypos = 0;
    unsigned long long key = 0;
    if (M[gid] && y >= RAD + 1 && y < HH - RAD && x >= RAD + 1 && x < WW - RAD) {
        float v = S[gid];
        if (v != 0.f) {
            unsigned bits = __float_as_uint(v);
            if ((int)(bits >> 16) >= Tbin[b]) {
                mypos = atomicAdd(&lcnt, 1u);
                key = ((unsigned long long)bits << 32) | (unsigned)(~(unsigned)p);
                win = true;
            }
        }
    }
    __syncthreads();
    if (threadIdx.x == 0 && lcnt)
        lbase = atomicAdd(&cnt[b * CNT_STRIDE], lcnt);
    __syncthreads();
    if (win) {
        unsigned pos = lbase + mypos;
        if (pos < CAND_CAP) cand[b * CAND_CAP + pos] = key;
    }
}

// one block per batch: bitonic-sort 8192 keys descending, emit top 4096 indices
__global__ __launch_bounds__(1024) void k_sort(const unsigned* __restrict__ cnt,
                                               const unsigned long long* __restrict__ cand,
                                               int* __restrict__ kp) {
    __shared__ unsigned long long keys[CAND_CAP];
    int b = blockIdx.x, t = threadIdx.x;
    unsigned nr = cnt[b * CNT_STRIDE];
    if (nr > CAND_CAP) nr = CAND_CAP;
    for (int i = t; i < CAND_CAP; i += 1024)
        keys[i] = (i < (int)nr) ? cand[b * CAND_CAP + i] : 0ull;
    __syncthreads();
    for (int k = 2; k <= CAND_CAP; k <<= 1) {
        for (int j = k >> 1; j > 0; j >>= 1) {
            for (int i = t; i < CAND_CAP; i += 1024) {
                int ixj = i ^ j;
                if (ixj > i) {
                    bool asc = (i & k) != 0;
                    unsigned long long a = keys[i], c = keys[ixj];
                    bool sw = asc ? (a > c) : (a < c);
                    if (sw) { keys[i] = c; keys[ixj] = a; }
                }
            }
            __syncthreads();
        }
    }
    for (int i = t; i < TOPK; i += 1024) {
        unsigned long long key = keys[i];
        int idx;
        if (key != 0ull) idx = (int)(~(unsigned)(key & 0xFFFFFFFFull));
        else             idx = i - (int)nr;
        kp[b * TOPK + i] = idx;
    }
}

// per-keypoint: softmax soft-argmax + disp + normalized coords + bilinear score
__global__ void k_kp(const float* __restrict__ S, const int* __restrict__ kp,
                     float* __restrict__ out) {
    int g = blockIdx.x * blockDim.x + threadIdx.x;
    if (g >= BN * TOPK) return;
    int b = g >> 12;
    int idx = kp[g];
    int y = idx / WW, x = idx - y * WW;
    const float* img = S + b * HWp;
    float ps[25];
#pragma unroll
    for (int di = 0; di < 5; ++di) {
#pragma unroll
        for (int dj = 0; dj < 5; ++dj) {
            int yy = y + di - RAD, xx = x + dj - RAD;
            bool ok = (yy >= 0) && (yy < HH) && (xx >= 0) && (xx < WW);
            ps[di * 5 + dj] = ok ? img[yy * WW + xx] : 0.f;
        }
    }
    float mx = ps[0];
#pragma unroll
    for (int p = 1; p < 25; ++p) mx = fmaxf(mx, ps[p]);
    float ssum = 0.f, sx = 0.f, sy = 0.f, sg2 = 0.f;
#pragma unroll
    for (int p = 0; p < 25; ++p) {
        float dx = (float)(p % 5) - 2.f;
        float dy = (float)(p / 5) - 2.f;
        float e = expf((ps[p] - mx) / 0.1f);
        ssum += e;
        sx += e * dx;
        sy += e * dy;
        sg2 += e * (dx * dx + dy * dy);
    }
    float xr = sx / ssum, yr = sy / ssum;
    float disp = (sg2 - 2.f * (xr * sx + yr * sy) + (xr * xr + yr * yr) * ssum)
                 / (4.f * ssum);
    float kxn = ((float)x + xr) / (float)(WW - 1) * 2.f - 1.f;
    float kyn = ((float)y + yr) / (float)(HH - 1) * 2.f - 1.f;
    out[2 * g]     = kxn;
    out[2 * g + 1] = kyn;
    float px = (kxn + 1.f) * 0.5f * (float)(WW - 1);
    float py = (kyn + 1.f) * 0.5f * (float)(HH - 1);
    float x0 = floorf(px), y0f = floorf(py);
    float wx = px - x0, wy = py - y0f;
    int x0i = (int)fminf(fmaxf(x0, 0.f), (float)(WW - 1));
    int x1i = (int)fminf(fmaxf(x0 + 1.f, 0.f), (float)(WW - 1));
    int y0i = (int)fminf(fmaxf(y0f, 0.f), (float)(HH - 1));
    int y1i = (int)fminf(fmaxf(y0f + 1.f, 0.f), (float)(HH - 1));
    float v00 = img[y0i * WW + x0i], v01 = img[y0i * WW + x1i];
    float v10 = img[y1i * WW + x0i], v11 = img[y1i * WW + x1i];
    float sc = v00 * (1.f - wx) * (1.f - wy) + v01 * wx * (1.f - wy)
             + v10 * (1.f - wx) * wy + v11 * wx * wy;
    out[BN * TOPK * 2 + g] = sc;
    out[BN * TOPK * 3 + g] = disp;
}

extern "C" void kernel_launch(void* const* d_in, const int* in_sizes, int n_in,
                              void* d_out, int out_size, void* d_ws, size_t ws_size,
                              hipStream_t stream) {
    const float* S = (const float*)d_in[0];
    float* out = (float*)d_out;
    char* ws = (char*)d_ws;

    uint8_t*            M     = (uint8_t*)(ws + OFF_M);
    unsigned*           hist  = (unsigned*)(ws + OFF_HIST);
    unsigned*           cnt   = (unsigned*)(ws + OFF_CNT);
    int*                Tbin  = (int*)(ws + OFF_TBIN);
    unsigned long long* cand  = (unsigned long long*)(ws + OFF_CAND);
    int*                kpidx = (int*)(ws + OFF_KPIDX);

    int zwords = (BN * NBINS * 4 + 1024) / 4;
    k_zero<<<(zwords + 255) / 256, 256, 0, stream>>>(hist, zwords);

    k_nms_fused<<<BN * GTX * GTY, 256, 0, stream>>>(S, M, hist);

    int nblk = (NPIX + 255) / 256;
    k_scan<<<BN, 1024, 0, stream>>>(hist, Tbin);
    k_compact<<<nblk, 256, 0, stream>>>(S, M, Tbin, cnt, cand);
    k_sort<<<BN, 1024, 0, stream>>>(cnt, cand, kpidx);
    k_kp<<<(BN * TOPK + 255) / 256, 256, 0, stream>>>(S, kpidx, out);
}

// Round 13
// 397.612 us; speedup vs baseline: 2.3774x; 1.0684x over previous
//
#include <hip/hip_runtime.h>
#include <cstdint>

#define BN 8
#define HH 512
#define WW 640
#define HWp (HH*WW)
#define NPIX (BN*HWp)
#define RAD 2
#define TOPK 4096
#define NBINS 65536
#define CAND_CAP 8192

// workspace layout (bytes)
#define OFF_M     0
#define OFF_U     (OFF_M + NPIX)
#define OFF_HIST  (OFF_U + NPIX)
#define OFF_CNT   (OFF_HIST + BN*NBINS*4)
#define OFF_TBIN  (OFF_CNT + 1024)
#define OFF_CAND  (OFF_TBIN + 128)
#define OFF_KPIDX (OFF_CAND + BN*CAND_CAP*8)

#define CNT_STRIDE 32   // uints; 128 bytes between per-batch counters

// fused-NMS tiling: 32x32 output tile, halo 10
#define TILE 32
#define HALO 10
#define STG  52          // TILE + 2*HALO
#define LSTR 56          // LDS row stride (floats); 56%4==0 -> rows 16B aligned
#define GTX  20          // 640/32 exact
#define GTY  16          // 512/32 exact

__global__ void k_zero(unsigned* __restrict__ p, int n) {
    int i = blockIdx.x * blockDim.x + threadIdx.x;
    if (i < n) p[i] = 0u;
}

__device__ __forceinline__ float4 f4max(float4 a, float4 b) {
    return make_float4(fmaxf(a.x,b.x), fmaxf(a.y,b.y), fmaxf(a.z,b.z), fmaxf(a.w,b.w));
}
__device__ __forceinline__ float4 f4supp(float4 u, float4 s) {
    return make_float4(u.x!=0.f?0.f:s.x, u.y!=0.f?0.f:s.y,
                       u.z!=0.f?0.f:s.z, u.w!=0.f?0.f:s.w);
}

// ---- one block = one 32x32 output tile: full simple_nms (2 iters) + hist ----
// all LDS traffic via float4 (ds_read_b128/ds_write_b128); masks stored as 0.0/1.0 floats
__global__ __launch_bounds__(256) void k_nms_fused(const float* __restrict__ S,
                                                   uint8_t* __restrict__ M,
                                                   unsigned* __restrict__ hist) {
    __shared__ float sm [STG][LSTR];
    __shared__ float tmp[STG][LSTR];
    __shared__ float mf [STG][LSTR];   // max_mask (0/1)
    __shared__ float uf [STG][LSTR];   // supp_mask (0/1)

    int bid = blockIdx.x;
    int b   = bid / (GTX * GTY);
    int t   = bid - b * (GTX * GTY);
    int tyy = t / GTX, txx = t - tyy * GTX;
    int oy = tyy * TILE - HALO;
    int ox = txx * TILE - HALO;
    const float* img = S + b * HWp;
    int tid = threadIdx.x;
    const float NEG = -__builtin_inff();

    // stage S (OOB = -inf, matching SAME max-pool padding)
    for (int idx = tid; idx < STG * STG; idx += 256) {
        int i = idx / STG, j = idx - i * STG;
        int Y = oy + i, X = ox + j;
        sm[i][j] = (Y >= 0 && Y < HH && X >= 0 && X < WW) ? img[Y * WW + X] : NEG;
    }
    __syncthreads();

    // ---- pass 1 vertical: tmp = vmax5(sm), rows [2,50), all 13 col-groups ----
    for (int idx = tid; idx < 48 * 13; idx += 256) {
        int r = idx / 13, g = idx - r * 13;
        int ci = r + 2, j4 = g * 4;
        float4 v0 = *(const float4*)&sm[ci-2][j4];
        float4 v1 = *(const float4*)&sm[ci-1][j4];
        float4 v2 = *(const float4*)&sm[ci  ][j4];
        float4 v3 = *(const float4*)&sm[ci+1][j4];
        float4 v4 = *(const float4*)&sm[ci+2][j4];
        *(float4*)&tmp[ci][j4] = f4max(f4max(f4max(v0,v1), f4max(v2,v3)), v4);
    }
    __syncthreads();
    // ---- pass 1 horizontal: mf = (sm == hmax5(tmp)) & valid, cols [2,50) ----
    for (int idx = tid; idx < 48 * 13; idx += 256) {
        int r = idx / 13, g = idx - r * 13;
        int ci = r + 2, jB = g * 4;
        int jA = jB ? jB - 4 : 0;
        float4 A = *(const float4*)&tmp[ci][jA];
        float4 Bv = *(const float4*)&tmp[ci][jB];
        float4 Cv = *(const float4*)&tmp[ci][jB+4];
        float w0=A.z, w1=A.w, w2=Bv.x, w3=Bv.y, w4=Bv.z, w5=Bv.w, w6=Cv.x, w7=Cv.y;
        float mr0 = fmaxf(fmaxf(fmaxf(w0,w1), fmaxf(w2,w3)), w4);
        float mr1 = fmaxf(fmaxf(fmaxf(w1,w2), fmaxf(w3,w4)), w5);
        float mr2 = fmaxf(fmaxf(fmaxf(w2,w3), fmaxf(w4,w5)), w6);
        float mr3 = fmaxf(fmaxf(fmaxf(w3,w4), fmaxf(w5,w6)), w7);
        float4 sc = *(const float4*)&sm[ci][jB];
        int Y = oy + ci;
        bool vy = (Y >= 0 && Y < HH);
        float o0=0.f,o1=0.f,o2=0.f,o3=0.f;
        int X0 = ox + jB;
        if (jB+0>=2 && jB+0<50 && vy && X0+0>=0 && X0+0<WW && sc.x==mr0) o0=1.f;
        if (jB+1>=2 && jB+1<50 && vy && X0+1>=0 && X0+1<WW && sc.y==mr1) o1=1.f;
        if (jB+2>=2 && jB+2<50 && vy && X0+2>=0 && X0+2<WW && sc.z==mr2) o2=1.f;
        if (jB+3>=2 && jB+3<50 && vy && X0+3>=0 && X0+3<WW && sc.w==mr3) o3=1.f;
        *(float4*)&mf[ci][jB] = make_float4(o0,o1,o2,o3);
    }
    __syncthreads();

    // ---- pass 2 vertical: tmp = vor5(mf), rows [4,48) ----
    for (int idx = tid; idx < 44 * 13; idx += 256) {
        int r = idx / 13, g = idx - r * 13;
        int ci = r + 4, j4 = g * 4;
        float4 v0 = *(const float4*)&mf[ci-2][j4];
        float4 v1 = *(const float4*)&mf[ci-1][j4];
        float4 v2 = *(const float4*)&mf[ci  ][j4];
        float4 v3 = *(const float4*)&mf[ci+1][j4];
        float4 v4 = *(const float4*)&mf[ci+2][j4];
        *(float4*)&tmp[ci][j4] = f4max(f4max(f4max(v0,v1), f4max(v2,v3)), v4);
    }
    __syncthreads();
    // ---- pass 2 horizontal: uf = hmax5(tmp) > 0, cols [4,48) (11 full groups) ----
    for (int idx = tid; idx < 44 * 11; idx += 256) {
        int r = idx / 11, g = idx - r * 11;
        int ci = r + 4, jB = (g + 1) * 4;
        float4 A = *(const float4*)&tmp[ci][jB-4];
        float4 Bv = *(const float4*)&tmp[ci][jB];
        float4 Cv = *(const float4*)&tmp[ci][jB+4];
        float w0=A.z, w1=A.w, w2=Bv.x, w3=Bv.y, w4=Bv.z, w5=Bv.w, w6=Cv.x, w7=Cv.y;
        float4 o;
        o.x = (fmaxf(fmaxf(fmaxf(w0,w1), fmaxf(w2,w3)), w4) > 0.f) ? 1.f : 0.f;
        o.y = (fmaxf(fmaxf(fmaxf(w1,w2), fmaxf(w3,w4)), w5) > 0.f) ? 1.f : 0.f;
        o.z = (fmaxf(fmaxf(fmaxf(w2,w3), fmaxf(w4,w5)), w6) > 0.f) ? 1.f : 0.f;
        o.w = (fmaxf(fmaxf(fmaxf(w3,w4), fmaxf(w5,w6)), w7) > 0.f) ? 1.f : 0.f;
        *(float4*)&uf[ci][jB] = o;
    }
    __syncthreads();

    // ---- pass 3 vertical: tmp = vmax5(supp), rows [6,46) ----
    for (int idx = tid; idx < 40 * 13; idx += 256) {
        int r = idx / 13, g = idx - r * 13;
        int ci = r + 6, j4 = g * 4;
        float4 p0 = f4supp(*(const float4*)&uf[ci-2][j4], *(const float4*)&sm[ci-2][j4]);
        float4 p1 = f4supp(*(const float4*)&uf[ci-1][j4], *(const float4*)&sm[ci-1][j4]);
        float4 p2 = f4supp(*(const float4*)&uf[ci  ][j4], *(const float4*)&sm[ci  ][j4]);
        float4 p3 = f4supp(*(const float4*)&uf[ci+1][j4], *(const float4*)&sm[ci+1][j4]);
        float4 p4 = f4supp(*(const float4*)&uf[ci+2][j4], *(const float4*)&sm[ci+2][j4]);
        *(float4*)&tmp[ci][j4] = f4max(f4max(f4max(p0,p1), f4max(p2,p3)), p4);
    }
    __syncthreads();
    // ---- pass 3 horizontal: mf |= (supp==hmax5) & ~uf & valid, cols [6,46) ----
    for (int idx = tid; idx < 40 * 11; idx += 256) {
        int r = idx / 11, g = idx - r * 11;
        int ci = r + 6, jB = (g + 1) * 4;
        float4 A = *(const float4*)&tmp[ci][jB-4];
        float4 Bv = *(const float4*)&tmp[ci][jB];
        float4 Cv = *(const float4*)&tmp[ci][jB+4];
        float w0=A.z, w1=A.w, w2=Bv.x, w3=Bv.y, w4=Bv.z, w5=Bv.w, w6=Cv.x, w7=Cv.y;
        float mr[4];
        mr[0] = fmaxf(fmaxf(fmaxf(w0,w1), fmaxf(w2,w3)), w4);
        mr[1] = fmaxf(fmaxf(fmaxf(w1,w2), fmaxf(w3,w4)), w5);
        mr[2] = fmaxf(fmaxf(fmaxf(w2,w3), fmaxf(w4,w5)), w6);
        mr[3] = fmaxf(fmaxf(fmaxf(w3,w4), fmaxf(w5,w6)), w7);
        float4 uB = *(const float4*)&uf[ci][jB];
        float4 sB = *(const float4*)&sm[ci][jB];
        float4 mB = *(float4*)&mf[ci][jB];
        float u[4] = {uB.x,uB.y,uB.z,uB.w};
        float s[4] = {sB.x,sB.y,sB.z,sB.w};
        float m[4] = {mB.x,mB.y,mB.z,mB.w};
        int Y = oy + ci;
        bool vy = (Y >= 0 && Y < HH);
#pragma unroll
        for (int k = 0; k < 4; ++k) {
            int cj = jB + k;
            if (cj >= 6 && cj < 46) {
                int X = ox + cj;
                bool valid = vy && X >= 0 && X < WW;
                float vc = (u[k] != 0.f) ? 0.f : s[k];
                if (valid && u[k] == 0.f && vc == mr[k]) m[k] = 1.f;
            }
        }
        *(float4*)&mf[ci][jB] = make_float4(m[0],m[1],m[2],m[3]);
    }
    __syncthreads();

    // ---- pass 4 vertical: tmp = vor5(mf), rows [8,44) ----
    for (int idx = tid; idx < 36 * 13; idx += 256) {
        int r = idx / 13, g = idx - r * 13;
        int ci = r + 8, j4 = g * 4;
        float4 v0 = *(const float4*)&mf[ci-2][j4];
        float4 v1 = *(const float4*)&mf[ci-1][j4];
        float4 v2 = *(const float4*)&mf[ci  ][j4];
        float4 v3 = *(const float4*)&mf[ci+1][j4];
        float4 v4 = *(const float4*)&mf[ci+2][j4];
        *(float4*)&tmp[ci][j4] = f4max(f4max(f4max(v0,v1), f4max(v2,v3)), v4);
    }
    __syncthreads();
    // ---- pass 4 horizontal: uf = hmax5(tmp) > 0, cols [8,44) (9 full groups) ----
    for (int idx = tid; idx < 36 * 9; idx += 256) {
        int r = idx / 9, g = idx - r * 9;
        int ci = r + 8, jB = (g + 2) * 4;
        float4 A = *(const float4*)&tmp[ci][jB-4];
        float4 Bv = *(const float4*)&tmp[ci][jB];
        float4 Cv = *(const float4*)&tmp[ci][jB+4];
        float w0=A.z, w1=A.w, w2=Bv.x, w3=Bv.y, w4=Bv.z, w5=Bv.w, w6=Cv.x, w7=Cv.y;
        float4 o;
        o.x = (fmaxf(fmaxf(fmaxf(w0,w1), fmaxf(w2,w3)), w4) > 0.f) ? 1.f : 0.f;
        o.y = (fmaxf(fmaxf(fmaxf(w1,w2), fmaxf(w3,w4)), w5) > 0.f) ? 1.f : 0.f;
        o.z = (fmaxf(fmaxf(fmaxf(w2,w3), fmaxf(w4,w5)), w6) > 0.f) ? 1.f : 0.f;
        o.w = (fmaxf(fmaxf(fmaxf(w3,w4), fmaxf(w5,w6)), w7) > 0.f) ? 1.f : 0.f;
        *(float4*)&uf[ci][jB] = o;
    }
    __syncthreads();

    // ---- pass 5 vertical: tmp = vmax5(supp2), rows [10,42) ----
    for (int idx = tid; idx < 32 * 13; idx += 256) {
        int r = idx / 13, g = idx - r * 13;
        int ci = r + 10, j4 = g * 4;
        float4 p0 = f4supp(*(const float4*)&uf[ci-2][j4], *(const float4*)&sm[ci-2][j4]);
        float4 p1 = f4supp(*(const float4*)&uf[ci-1][j4], *(const float4*)&sm[ci-1][j4]);
        float4 p2 = f4supp(*(const float4*)&uf[ci  ][j4], *(const float4*)&sm[ci  ][j4]);
        float4 p3 = f4supp(*(const float4*)&uf[ci+1][j4], *(const float4*)&sm[ci+1][j4]);
        float4 p4 = f4supp(*(const float4*)&uf[ci+2][j4], *(const float4*)&sm[ci+2][j4]);
        *(float4*)&tmp[ci][j4] = f4max(f4max(f4max(p0,p1), f4max(p2,p3)), p4);
    }
    __syncthreads();
    // ---- pass 5 horizontal: final mask + M write + hist, cols [10,42) ----
    for (int idx = tid; idx < 32 * 9; idx += 256) {
        int r = idx / 9, g = idx - r * 9;
        int ci = r + 10, jB = (g + 2) * 4;
        float4 A = *(const float4*)&tmp[ci][jB-4];
        float4 Bv = *(const float4*)&tmp[ci][jB];
        float4 Cv = *(const float4*)&tmp[ci][jB+4];
        float w0=A.z, w1=A.w, w2=Bv.x, w3=Bv.y, w4=Bv.z, w5=Bv.w, w6=Cv.x, w7=Cv.y;
        float mr[4];
        mr[0] = fmaxf(fmaxf(fmaxf(w0,w1), fmaxf(w2,w3)), w4);
        mr[1] = fmaxf(fmaxf(fmaxf(w1,w2), fmaxf(w3,w4)), w5);
        mr[2] = fmaxf(fmaxf(fmaxf(w2,w3), fmaxf(w4,w5)), w6);
        mr[3] = fmaxf(fmaxf(fmaxf(w3,w4), fmaxf(w5,w6)), w7);
        float4 uB = *(const float4*)&uf[ci][jB];
        float4 sB = *(const float4*)&sm[ci][jB];
        float4 mB = *(const float4*)&mf[ci][jB];
        float u[4] = {uB.x,uB.y,uB.z,uB.w};
        float s[4] = {sB.x,sB.y,sB.z,sB.w};
        float m[4] = {mB.x,mB.y,mB.z,mB.w};
        int Y = oy + ci;
#pragma unroll
        for (int k = 0; k < 4; ++k) {
            int cj = jB + k;
            if (cj >= 10 && cj < 42) {
                int X = ox + cj;
                float cv = s[k];
                float vc = (u[k] != 0.f) ? 0.f : cv;
                uint8_t m3 = (m[k] != 0.f) ? (uint8_t)1 : (uint8_t)0;
                if (u[k] == 0.f && vc == mr[k]) m3 = 1;
                M[b * HWp + Y * WW + X] = m3;
                if (m3 && Y >= RAD + 1 && Y < HH - RAD && X >= RAD + 1 && X < WW - RAD
                    && cv != 0.f) {
                    unsigned bits = __float_as_uint(cv);
                    atomicAdd(&hist[b * NBINS + (bits >> 16)], 1u);
                }
            }
        }
    }
}

// per-batch: threshold bin T s.t. count(bins > T) < TOPK <= count(bins >= T)
__global__ __launch_bounds__(1024) void k_scan(const unsigned* __restrict__ hist,
                                               int* __restrict__ Tbin) {
    __shared__ unsigned b0[1024], b1[1024];
    int b = blockIdx.x, t = threadIdx.x;
    const unsigned* h = hist + b * NBINS;
    int base = NBINS - (t + 1) * 64;
    unsigned s = 0;
    for (int i = 0; i < 64; ++i) s += h[base + i];
    b0[t] = s;
    __syncthreads();
    unsigned* src = b0; unsigned* dst = b1;
    for (int off = 1; off < 1024; off <<= 1) {
        unsigned v = src[t];
        if (t >= off) v += src[t - off];
        dst[t] = v;
        __syncthreads();
        unsigned* tmp2 = src; src = dst; dst = tmp2;
    }
    unsigned incl = src[t];
    unsigned excl = incl - s;
    unsigned total = src[1023];
    const unsigned K = TOPK;
    if (excl < K && K <= incl) {
        unsigned run = excl;
        for (int i = 0; i < 64; ++i) {
            int bin = NBINS - 1 - t * 64 - i;
            unsigned c = h[bin];
            if (run < K && K <= run + c) { Tbin[b] = bin; break; }
            run += c;
        }
    }
    if (t == 1023 && total < K) Tbin[b] = 0;
}

// vectorized block-aggregated compaction: 4 pixels/thread, early-skip via uint M read
__global__ void k_compact4(const float* __restrict__ S, const uint8_t* __restrict__ M,
                           const int* __restrict__ Tbin,
                           unsigned* __restrict__ cnt, unsigned long long* __restrict__ cand) {
    __shared__ unsigned lcnt, lbase;
    int g = blockIdx.x * 256 + threadIdx.x;
    int gid4 = g * 4;
    int b = gid4 / HWp, p = gid4 - b * HWp;
    int y = p / WW, x0 = p - y * WW;
    if (threadIdx.x == 0) lcnt = 0;
    __syncthreads();
    unsigned long long mykeys[4];
    int myn = 0;
    unsigned mw = *(const unsigned*)(M + gid4);
    if (mw && y >= RAD + 1 && y < HH - RAD) {
        int Tb = Tbin[b];
#pragma unroll
        for (int i = 0; i < 4; ++i) {
            if ((mw >> (8 * i)) & 0xFFu) {
                int x = x0 + i;
                if (x >= RAD + 1 && x < WW - RAD) {
                    float v = S[gid4 + i];
                    if (v != 0.f) {
                        unsigned bits = __float_as_uint(v);
                        if ((int)(bits >> 16) >= Tb)
                            mykeys[myn++] = ((unsigned long long)bits << 32)
                                          | (unsigned)(~(unsigned)(p + i));
                    }
                }
            }
        }
    }
    unsigned base_l = 0;
    if (myn) base_l = atomicAdd(&lcnt, (unsigned)myn);
    __syncthreads();
    if (threadIdx.x == 0 && lcnt)
        lbase = atomicAdd(&cnt[b * CNT_STRIDE], lcnt);
    __syncthreads();
    for (int i = 0; i < myn; ++i) {
        unsigned pos = lbase + base_l + (unsigned)i;
        if (pos < CAND_CAP) cand[b * CAND_CAP + pos] = mykeys[i];
    }
}

// one block per batch: bitonic-sort 8192 keys descending, emit top 4096 indices
__global__ __launch_bounds__(1024) void k_sort(const unsigned* __restrict__ cnt,
                                               const unsigned long long* __restrict__ cand,
                                               int* __restrict__ kp) {
    __shared__ unsigned long long keys[CAND_CAP];
    int b = blockIdx.x, t = threadIdx.x;
    unsigned nr = cnt[b * CNT_STRIDE];
    if (nr > CAND_CAP) nr = CAND_CAP;
    for (int i = t; i < CAND_CAP; i += 1024)
        keys[i] = (i < (int)nr) ? cand[b * CAND_CAP + i] : 0ull;
    __syncthreads();
    for (int k = 2; k <= CAND_CAP; k <<= 1) {
        for (int j = k >> 1; j > 0; j >>= 1) {
            for (int i = t; i < CAND_CAP; i += 1024) {
                int ixj = i ^ j;
                if (ixj > i) {
                    bool asc = (i & k) != 0;
                    unsigned long long a = keys[i], c = keys[ixj];
                    bool sw = asc ? (a > c) : (a < c);
                    if (sw) { keys[i] = c; keys[ixj] = a; }
                }
            }
            __syncthreads();
        }
    }
    for (int i = t; i < TOPK; i += 1024) {
        unsigned long long key = keys[i];
        int idx;
        if (key != 0ull) idx = (int)(~(unsigned)(key & 0xFFFFFFFFull));
        else             idx = i - (int)nr;
        kp[b * TOPK + i] = idx;
    }
}

// per-keypoint: softmax soft-argmax + disp + normalized coords + bilinear score
__global__ void k_kp(const float* __restrict__ S, const int* __restrict__ kp,
                     float* __restrict__ out) {
    int g = blockIdx.x * blockDim.x + threadIdx.x;
    if (g >= BN * TOPK) return;
    int b = g >> 12;
    int idx = kp[g];
    int y = idx / WW, x = idx - y * WW;
    const float* img = S + b * HWp;
    float ps[25];
#pragma unroll
    for (int di = 0; di < 5; ++di) {
#pragma unroll
        for (int dj = 0; dj < 5; ++dj) {
            int yy = y + di - RAD, xx = x + dj - RAD;
            bool ok = (yy >= 0) && (yy < HH) && (xx >= 0) && (xx < WW);
            ps[di * 5 + dj] = ok ? img[yy * WW + xx] : 0.f;
        }
    }
    float mx = ps[0];
#pragma unroll
    for (int p = 1; p < 25; ++p) mx = fmaxf(mx, ps[p]);
    float ssum = 0.f, sx = 0.f, sy = 0.f, sg2 = 0.f;
#pragma unroll
    for (int p = 0; p < 25; ++p) {
        float dx = (float)(p % 5) - 2.f;
        float dy = (float)(p / 5) - 2.f;
        float e = expf((ps[p] - mx) / 0.1f);
        ssum += e;
        sx += e * dx;
        sy += e * dy;
        sg2 += e * (dx * dx + dy * dy);
    }
    float xr = sx / ssum, yr = sy / ssum;
    float disp = (sg2 - 2.f * (xr * sx + yr * sy) + (xr * xr + yr * yr) * ssum)
                 / (4.f * ssum);
    float kxn = ((float)x + xr) / (float)(WW - 1) * 2.f - 1.f;
    float kyn = ((float)y + yr) / (float)(HH - 1) * 2.f - 1.f;
    out[2 * g]     = kxn;
    out[2 * g + 1] = kyn;
    float px = (kxn + 1.f) * 0.5f * (float)(WW - 1);
    float py = (kyn + 1.f) * 0.5f * (float)(HH - 1);
    float x0 = floorf(px), y0f = floorf(py);
    float wx = px - x0, wy = py - y0f;
    int x0i = (int)fminf(fmaxf(x0, 0.f), (float)(WW - 1));
    int x1i = (int)fminf(fmaxf(x0 + 1.f, 0.f), (float)(WW - 1));
    int y0i = (int)fminf(fmaxf(y0f, 0.f), (float)(HH - 1));
    int y1i = (int)fminf(fmaxf(y0f + 1.f, 0.f), (float)(HH - 1));
    float v00 = img[y0i * WW + x0i], v01 = img[y0i * WW + x1i];
    float v10 = img[y1i * WW + x0i], v11 = img[y1i * WW + x1i];
    float sc = v00 * (1.f - wx) * (1.f - wy) + v01 * wx * (1.f - wy)
             + v10 * (1.f - wx) * wy + v11 * wx * wy;
    out[BN * TOPK * 2 + g] = sc;
    out[BN * TOPK * 3 + g] = disp;
}

extern "C" void kernel_launch(void* const* d_in, const int* in_sizes, int n_in,
                              void* d_out, int out_size, void* d_ws, size_t ws_size,
                              hipStream_t stream) {
    const float* S = (const float*)d_in[0];
    float* out = (float*)d_out;
    char* ws = (char*)d_ws;

    uint8_t*            M     = (uint8_t*)(ws + OFF_M);
    unsigned*           hist  = (unsigned*)(ws + OFF_HIST);
    unsigned*           cnt   = (unsigned*)(ws + OFF_CNT);
    int*                Tbin  = (int*)(ws + OFF_TBIN);
    unsigned long long* cand  = (unsigned long long*)(ws + OFF_CAND);
    int*                kpidx = (int*)(ws + OFF_KPIDX);

    int zwords = (BN * NBINS * 4 + 1024) / 4;
    k_zero<<<(zwords + 255) / 256, 256, 0, stream>>>(hist, zwords);

    k_nms_fused<<<BN * GTX * GTY, 256, 0, stream>>>(S, M, hist);

    k_scan<<<BN, 1024, 0, stream>>>(hist, Tbin);
    k_compact4<<<NPIX / 4 / 256, 256, 0, stream>>>(S, M, Tbin, cnt, cand);
    k_sort<<<BN, 1024, 0, stream>>>(cnt, cand, kpidx);
    k_kp<<<(BN * TOPK + 255) / 256, 256, 0, stream>>>(S, kpidx, out);
}

// Round 16
// 385.984 us; speedup vs baseline: 2.4490x; 1.0301x over previous
//
#include <hip/hip_runtime.h>
#include <cstdint>

#define BN 8
#define HH 512
#define WW 640
#define HWp (HH*WW)
#define NPIX (BN*HWp)
#define RAD 2
#define TOPK 4096
#define NBINS 65536
#define CAND_CAP 8192

// workspace layout (bytes)
#define OFF_M     0
#define OFF_U     (OFF_M + NPIX)
#define OFF_HIST  (OFF_U + NPIX)
#define OFF_CNT   (OFF_HIST + BN*NBINS*4)
#define OFF_TBIN  (OFF_CNT + 1024)
#define OFF_CAND  (OFF_TBIN + 128)
#define OFF_KPIDX (OFF_CAND + BN*CAND_CAP*8)

#define CNT_STRIDE 32   // uints; 128 bytes between per-batch counters

// fused-NMS tiling: 32x32 output tile, halo 10 -> 29.1 KB LDS; 512 thr -> 4 blocks/CU (100% occ)
#define TILE 32
#define HALO 10
#define STG  52          // TILE + 2*HALO
#define LSTR 56          // LDS row stride (floats)
#define GTX  20          // 640/32 exact
#define GTY  16          // 512/32 exact
#define NMS_T 512

__global__ void k_zero(unsigned* __restrict__ p, int n) {
    int i = blockIdx.x * blockDim.x + threadIdx.x;
    if (i < n) p[i] = 0u;
}

// ---- one block = one 32x32 output tile: full simple_nms (2 iters) + hist ----
__global__ __launch_bounds__(NMS_T) void k_nms_fused(const float* __restrict__ S,
                                                     uint8_t* __restrict__ M,
                                                     unsigned* __restrict__ hist) {
    __shared__ float   sm [STG][LSTR];
    __shared__ float   tmp[STG][LSTR];
    __shared__ uint8_t mbuf[STG][LSTR];
    __shared__ uint8_t ubuf[STG][LSTR];

    int bid = blockIdx.x;
    int b   = bid / (GTX * GTY);
    int t   = bid - b * (GTX * GTY);
    int tyy = t / GTX, txx = t - tyy * GTX;
    int oy = tyy * TILE - HALO;
    int ox = txx * TILE - HALO;
    const float* img = S + b * HWp;
    int tid = threadIdx.x;
    const float NEG = -__builtin_inff();

    // stage S (OOB = -inf, matching SAME max-pool padding)
    for (int idx = tid; idx < STG * STG; idx += NMS_T) {
        int i = idx / STG, j = idx - i * STG;
        int Y = oy + i, X = ox + j;
        sm[i][j] = (Y >= 0 && Y < HH && X >= 0 && X < WW) ? img[Y * WW + X] : NEG;
    }
    __syncthreads();

    // ---- pass 1: mask = (s == maxpool5(s)), centers [2,50)^2 (48 wide) ----
    for (int idx = tid; idx < 48 * STG; idx += NMS_T) {        // vertical
        int r = idx / STG, j = idx - r * STG;
        int ci = r + 2;
        float m0 = fmaxf(fmaxf(sm[ci-2][j], sm[ci-1][j]),
                         fmaxf(sm[ci][j],   sm[ci+1][j]));
        tmp[ci][j] = fmaxf(m0, sm[ci+2][j]);
    }
    __syncthreads();
    for (int idx = tid; idx < 48 * 48; idx += NMS_T) {         // horizontal
        int r = idx / 48, c = idx - r * 48;
        int ci = r + 2, cj = c + 2;
        float mx = fmaxf(fmaxf(tmp[ci][cj-2], tmp[ci][cj-1]),
                         fmaxf(fmaxf(tmp[ci][cj], tmp[ci][cj+1]), tmp[ci][cj+2]));
        int Y = oy + ci, X = ox + cj;
        bool valid = (Y >= 0 && Y < HH && X >= 0 && X < WW);
        mbuf[ci][cj] = (valid && sm[ci][cj] == mx) ? (uint8_t)1 : (uint8_t)0;
    }
    __syncthreads();

    // ---- pass 2: u1 = dilate5(m), centers [4,48)^2 (44 wide) ----
    for (int idx = tid; idx < 44 * STG; idx += NMS_T) {
        int r = idx / STG, j = idx - r * STG;
        int ci = r + 4;
        int acc = mbuf[ci-2][j] | mbuf[ci-1][j] | mbuf[ci][j]
                | mbuf[ci+1][j] | mbuf[ci+2][j];
        tmp[ci][j] = (float)acc;
    }
    __syncthreads();
    for (int idx = tid; idx < 44 * 44; idx += NMS_T) {
        int r = idx / 44, c = idx - r * 44;
        int ci = r + 4, cj = c + 4;
        float mx = fmaxf(fmaxf(tmp[ci][cj-2], tmp[ci][cj-1]),
                         fmaxf(fmaxf(tmp[ci][cj], tmp[ci][cj+1]), tmp[ci][cj+2]));
        ubuf[ci][cj] = (mx > 0.f) ? (uint8_t)1 : (uint8_t)0;
    }
    __syncthreads();

    // ---- pass 3: update1: m |= (supp==maxpool5(supp)) & ~u1, centers [6,46)^2 ----
    for (int idx = tid; idx < 40 * STG; idx += NMS_T) {
        int r = idx / STG, j = idx - r * STG;
        int ci = r + 6;
        float v0 = ubuf[ci-2][j] ? 0.f : sm[ci-2][j];
        float v1 = ubuf[ci-1][j] ? 0.f : sm[ci-1][j];
        float v2 = ubuf[ci  ][j] ? 0.f : sm[ci  ][j];
        float v3 = ubuf[ci+1][j] ? 0.f : sm[ci+1][j];
        float v4 = ubuf[ci+2][j] ? 0.f : sm[ci+2][j];
        tmp[ci][j] = fmaxf(fmaxf(fmaxf(v0, v1), fmaxf(v2, v3)), v4);
    }
    __syncthreads();
    for (int idx = tid; idx < 40 * 40; idx += NMS_T) {
        int r = idx / 40, c = idx - r * 40;
        int ci = r + 6, cj = c + 6;
        float mx = fmaxf(fmaxf(tmp[ci][cj-2], tmp[ci][cj-1]),
                         fmaxf(fmaxf(tmp[ci][cj], tmp[ci][cj+1]), tmp[ci][cj+2]));
        uint8_t u = ubuf[ci][cj];
        float vc = u ? 0.f : sm[ci][cj];
        int Y = oy + ci, X = ox + cj;
        bool valid = (Y >= 0 && Y < HH && X >= 0 && X < WW);
        if (valid && !u && vc == mx) mbuf[ci][cj] = 1;
    }
    __syncthreads();

    // ---- pass 4: u2 = dilate5(m2), centers [8,44)^2 ----
    for (int idx = tid; idx < 36 * STG; idx += NMS_T) {
        int r = idx / STG, j = idx - r * STG;
        int ci = r + 8;
        int acc = mbuf[ci-2][j] | mbuf[ci-1][j] | mbuf[ci][j]
                | mbuf[ci+1][j] | mbuf[ci+2][j];
        tmp[ci][j] = (float)acc;
    }
    __syncthreads();
    for (int idx = tid; idx < 36 * 36; idx += NMS_T) {
        int r = idx / 36, c = idx - r * 36;
        int ci = r + 8, cj = c + 8;
        float mx = fmaxf(fmaxf(tmp[ci][cj-2], tmp[ci][cj-1]),
                         fmaxf(fmaxf(tmp[ci][cj], tmp[ci][cj+1]), tmp[ci][cj+2]));
        ubuf[ci][cj] = (mx > 0.f) ? (uint8_t)1 : (uint8_t)0;
    }
    __syncthreads();

    // ---- pass 5: update2 + emit M + hist, centers [10,42)^2 (32x32 output) ----
    for (int idx = tid; idx < 32 * STG; idx += NMS_T) {
        int r = idx / STG, j = idx - r * STG;
        int ci = r + 10;
        float v0 = ubuf[ci-2][j] ? 0.f : sm[ci-2][j];
        float v1 = ubuf[ci-1][j] ? 0.f : sm[ci-1][j];
        float v2 = ubuf[ci  ][j] ? 0.f : sm[ci  ][j];
        float v3 = ubuf[ci+1][j] ? 0.f : sm[ci+1][j];
        float v4 = ubuf[ci+2][j] ? 0.f : sm[ci+2][j];
        tmp[ci][j] = fmaxf(fmaxf(fmaxf(v0, v1), fmaxf(v2, v3)), v4);
    }
    __syncthreads();
    for (int idx = tid; idx < 32 * 32; idx += NMS_T) {
        int r = idx >> 5, c = idx & 31;
        int ci = r + 10, cj = c + 10;
        int Y = oy + ci, X = ox + cj;
        float mx = fmaxf(fmaxf(tmp[ci][cj-2], tmp[ci][cj-1]),
                         fmaxf(fmaxf(tmp[ci][cj], tmp[ci][cj+1]), tmp[ci][cj+2]));
        uint8_t u = ubuf[ci][cj];
        float cv = sm[ci][cj];
        float vc = u ? 0.f : cv;
        uint8_t m3 = mbuf[ci][cj];
        if (!u && vc == mx) m3 = 1;
        M[b * HWp + Y * WW + X] = m3;
        if (m3 && Y >= RAD + 1 && Y < HH - RAD && X >= RAD + 1 && X < WW - RAD
            && cv != 0.f) {
            unsigned bits = __float_as_uint(cv);
            atomicAdd(&hist[b * NBINS + (bits >> 16)], 1u);
        }
    }
}

// per-batch: threshold bin T s.t. count(bins > T) < TOPK <= count(bins >= T)
__global__ __launch_bounds__(1024) void k_scan(const unsigned* __restrict__ hist,
                                               int* __restrict__ Tbin) {
    __shared__ unsigned b0[1024], b1[1024];
    int b = blockIdx.x, t = threadIdx.x;
    const unsigned* h = hist + b * NBINS;
    int base = NBINS - (t + 1) * 64;
    unsigned s = 0;
    const uint4* h4 = (const uint4*)(h + base);
#pragma unroll
    for (int i = 0; i < 16; ++i) {
        uint4 v = h4[i];
        s += v.x + v.y + v.z + v.w;
    }
    b0[t] = s;
    __syncthreads();
    unsigned* src = b0; unsigned* dst = b1;
    for (int off = 1; off < 1024; off <<= 1) {
        unsigned v = src[t];
        if (t >= off) v += src[t - off];
        dst[t] = v;
        __syncthreads();
        unsigned* tmp2 = src; src = dst; dst = tmp2;
    }
    unsigned incl = src[t];
    unsigned excl = incl - s;
    unsigned total = src[1023];
    const unsigned K = TOPK;
    if (excl < K && K <= incl) {
        unsigned run = excl;
        for (int i = 0; i < 64; ++i) {
            int bin = NBINS - 1 - t * 64 - i;
            unsigned c = h[bin];
            if (run < K && K <= run + c) { Tbin[b] = bin; break; }
            run += c;
        }
    }
    if (t == 1023 && total < K) Tbin[b] = 0;
}

// vectorized block-aggregated compaction: 4 pixels/thread, early-skip via uint M read
__global__ void k_compact4(const float* __restrict__ S, const uint8_t* __restrict__ M,
                           const int* __restrict__ Tbin,
                           unsigned* __restrict__ cnt, unsigned long long* __restrict__ cand) {
    __shared__ unsigned lcnt, lbase;
    int g = blockIdx.x * 256 + threadIdx.x;
    int gid4 = g * 4;
    int b = gid4 / HWp, p = gid4 - b * HWp;
    int y = p / WW, x0 = p - y * WW;
    if (threadIdx.x == 0) lcnt = 0;
    __syncthreads();
    unsigned long long mykeys[4];
    int myn = 0;
    unsigned mw = *(const unsigned*)(M + gid4);
    if (mw && y >= RAD + 1 && y < HH - RAD) {
        int Tb = Tbin[b];
#pragma unroll
        for (int i = 0; i < 4; ++i) {
            if ((mw >> (8 * i)) & 0xFFu) {
                int x = x0 + i;
                if (x >= RAD + 1 && x < WW - RAD) {
                    float v = S[gid4 + i];
                    if (v != 0.f) {
                        unsigned bits = __float_as_uint(v);
                        if ((int)(bits >> 16) >= Tb)
                            mykeys[myn++] = ((unsigned long long)bits << 32)
                                          | (unsigned)(~(unsigned)(p + i));
                    }
                }
            }
        }
    }
    unsigned base_l = 0;
    if (myn) base_l = atomicAdd(&lcnt, (unsigned)myn);
    __syncthreads();
    if (threadIdx.x == 0 && lcnt)
        lbase = atomicAdd(&cnt[b * CNT_STRIDE], lcnt);
    __syncthreads();
    for (int i = 0; i < myn; ++i) {
        unsigned pos = lbase + base_l + (unsigned)i;
        if (pos < CAND_CAP) cand[b * CAND_CAP + pos] = mykeys[i];
    }
}

// one block per batch: bitonic-sort 8192 keys descending, emit top 4096 indices
__global__ __launch_bounds__(1024) void k_sort(const unsigned* __restrict__ cnt,
                                               const unsigned long long* __restrict__ cand,
                                               int* __restrict__ kp) {
    __shared__ unsigned long long keys[CAND_CAP];
    int b = blockIdx.x, t = threadIdx.x;
    unsigned nr = cnt[b * CNT_STRIDE];
    if (nr > CAND_CAP) nr = CAND_CAP;
    for (int i = t; i < CAND_CAP; i += 1024)
        keys[i] = (i < (int)nr) ? cand[b * CAND_CAP + i] : 0ull;
    __syncthreads();
    for (int k = 2; k <= CAND_CAP; k <<= 1) {
        for (int j = k >> 1; j > 0; j >>= 1) {
            for (int i = t; i < CAND_CAP; i += 1024) {
                int ixj = i ^ j;
                if (ixj > i) {
                    bool asc = (i & k) != 0;
                    unsigned long long a = keys[i], c = keys[ixj];
                    bool sw = asc ? (a > c) : (a < c);
                    if (sw) { keys[i] = c; keys[ixj] = a; }
                }
            }
            __syncthreads();
        }
    }
    for (int i = t; i < TOPK; i += 1024) {
        unsigned long long key = keys[i];
        int idx;
        if (key != 0ull) idx = (int)(~(unsigned)(key & 0xFFFFFFFFull));
        else             idx = i - (int)nr;
        kp[b * TOPK + i] = idx;
    }
}

// per-keypoint: softmax soft-argmax + disp + normalized coords + bilinear score
__global__ void k_kp(const float* __restrict__ S, const int* __restrict__ kp,
                     float* __restrict__ out) {
    int g = blockIdx.x * blockDim.x + threadIdx.x;
    if (g >= BN * TOPK) return;
    int b = g >> 12;
    int idx = kp[g];
    int y = idx / WW, x = idx - y * WW;
    const float* img = S + b * HWp;
    float ps[25];
#pragma unroll
    for (int di = 0; di < 5; ++di) {
#pragma unroll
        for (int dj = 0; dj < 5; ++dj) {
            int yy = y + di - RAD, xx = x + dj - RAD;
            bool ok = (yy >= 0) && (yy < HH) && (xx >= 0) && (xx < WW);
            ps[di * 5 + dj] = ok ? img[yy * WW + xx] : 0.f;
        }
    }
    float mx = ps[0];
#pragma unroll
    for (int p = 1; p < 25; ++p) mx = fmaxf(mx, ps[p]);
    float ssum = 0.f, sx = 0.f, sy = 0.f, sg2 = 0.f;
#pragma unroll
    for (int p = 0; p < 25; ++p) {
        float dx = (float)(p % 5) - 2.f;
        float dy = (float)(p / 5) - 2.f;
        float e = __expf((ps[p] - mx) * 10.f);
        ssum += e;
        sx += e * dx;
        sy += e * dy;
        sg2 += e * (dx * dx + dy * dy);
    }
    float xr = sx / ssum, yr = sy / ssum;
    float disp = (sg2 - 2.f * (xr * sx + yr * sy) + (xr * xr + yr * yr) * ssum)
                 / (4.f * ssum);
    float kxn = ((float)x + xr) / (float)(WW - 1) * 2.f - 1.f;
    float kyn = ((float)y + yr) / (float)(HH - 1) * 2.f - 1.f;
    out[2 * g]     = kxn;
    out[2 * g + 1] = kyn;
    float px = (kxn + 1.f) * 0.5f * (float)(WW - 1);
    float py = (kyn + 1.f) * 0.5f * (float)(HH - 1);
    float x0 = floorf(px), y0f = floorf(py);
    float wx = px - x0, wy = py - y0f;
    int x0i = (int)fminf(fmaxf(x0, 0.f), (float)(WW - 1));
    int x1i = (int)fminf(fmaxf(x0 + 1.f, 0.f), (float)(WW - 1));
    int y0i = (int)fminf(fmaxf(y0f, 0.f), (float)(HH - 1));
    int y1i = (int)fminf(fmaxf(y0f + 1.f, 0.f), (float)(HH - 1));
    float v00 = img[y0i * WW + x0i], v01 = img[y0i * WW + x1i];
    float v10 = img[y1i * WW + x0i], v11 = img[y1i * WW + x1i];
    float sc = v00 * (1.f - wx) * (1.f - wy) + v01 * wx * (1.f - wy)
             + v10 * (1.f - wx) * wy + v11 * wx * wy;
    out[BN * TOPK * 2 + g] = sc;
    out[BN * TOPK * 3 + g] = disp;
}

extern "C" void kernel_launch(void* const* d_in, const int* in_sizes, int n_in,
                              void* d_out, int out_size, void* d_ws, size_t ws_size,
                              hipStream_t stream) {
    const float* S = (const float*)d_in[0];
    float* out = (float*)d_out;
    char* ws = (char*)d_ws;

    uint8_t*            M     = (uint8_t*)(ws + OFF_M);
    unsigned*           hist  = (unsigned*)(ws + OFF_HIST);
    unsigned*           cnt   = (unsigned*)(ws + OFF_CNT);
    int*                Tbin  = (int*)(ws + OFF_TBIN);
    unsigned long long* cand  = (unsigned long long*)(ws + OFF_CAND);
    int*                kpidx = (int*)(ws + OFF_KPIDX);

    int zwords = (BN * NBINS * 4 + 1024) / 4;
    k_zero<<<(zwords + 255) / 256, 256, 0, stream>>>(hist, zwords);

    k_nms_fused<<<BN * GTX * GTY, NMS_T, 0, stream>>>(S, M, hist);

    k_scan<<<BN, 1024, 0, stream>>>(hist, Tbin);
    k_compact4<<<NPIX / 4 / 256, 256, 0, stream>>>(S, M, Tbin, cnt, cand);
    k_sort<<<BN, 1024, 0, stream>>>(cnt, cand, kpidx);
    k_kp<<<(BN * TOPK + 255) / 256, 256, 0, stream>>>(S, kpidx, out);
}